// Round 1
// baseline (637.955 us; speedup 1.0000x reference)
//
#include <hip/hip_runtime.h>
#include <hip/hip_bf16.h>

#define N_NODES 20000
#define N_EDGES 320000
#define F_IN 256
#define HID 64
#define HEADS 8
#define NCLS 64
#define D1 (HEADS * HID)   // 512
#define NEG_SLOPE 0.2f

// ---------- helpers ----------
__device__ __forceinline__ unsigned fflip(float f) {
    unsigned u = __float_as_uint(f);
    return (u & 0x80000000u) ? ~u : (u | 0x80000000u);
}
__device__ __forceinline__ float funflip(unsigned s) {
    unsigned u = (s & 0x80000000u) ? (s & 0x7fffffffu) : ~s;
    return __uint_as_float(u);
}

// ---------- CSR build ----------
__global__ void hist_kernel(const int* __restrict__ dst, int* __restrict__ cnt, int E) {
    int i = blockIdx.x * 256 + threadIdx.x;
    if (i < E) atomicAdd(&cnt[dst[i]], 1);
}

__global__ void scan_kernel(const int* __restrict__ cnt, int* __restrict__ row_ptr,
                            int* __restrict__ cursor, int n) {
    __shared__ int sdata[256];
    __shared__ int s_off;
    int tid = threadIdx.x;
    if (tid == 0) { s_off = 0; row_ptr[0] = 0; }
    __syncthreads();
    for (int base = 0; base < n; base += 256) {
        int i = base + tid;
        int v = (i < n) ? cnt[i] : 0;
        sdata[tid] = v;
        __syncthreads();
        #pragma unroll
        for (int d = 1; d < 256; d <<= 1) {
            int x = (tid >= d) ? sdata[tid - d] : 0;
            __syncthreads();
            sdata[tid] += x;
            __syncthreads();
        }
        int inc = sdata[tid];
        int off = s_off;
        if (i < n) {
            row_ptr[i + 1] = off + inc;
            cursor[i] = off + inc - v;   // exclusive
        }
        __syncthreads();
        if (tid == 255) s_off = off + inc;
        __syncthreads();
    }
}

__global__ void scatter_kernel(const int* __restrict__ src, const int* __restrict__ dst,
                               int* __restrict__ cursor, int* __restrict__ csr_src, int E) {
    int i = blockIdx.x * 256 + threadIdx.x;
    if (i < E) {
        int d = dst[i];
        int pos = atomicAdd(&cursor[d], 1);
        csr_src[pos] = src[i];
    }
}

// ---------- fp32 tiled GEMM: C[M,N] = A[M,K] @ B[K,N] ----------
// 64x64 tile, 256 threads, 4x4 per thread. K multiple of 16, N multiple of 64.
__global__ __launch_bounds__(256) void gemm_tile(
    const float* __restrict__ A, const float* __restrict__ B, float* __restrict__ C,
    int M, int N, int K) {
    __shared__ float As[16][68];  // transposed A tile, stride 68 keeps 16B align
    __shared__ float Bs[16][64];
    int tid = threadIdx.x;
    int rowBase = blockIdx.y * 64;
    int colBase = blockIdx.x * 64;
    int tr = tid >> 4, tc = tid & 15;
    float acc[4][4] = {};
    for (int k0 = 0; k0 < K; k0 += 16) {
        {
            int r = tid >> 2;
            int k4 = (tid & 3) * 4;
            int row = rowBase + r;
            float4 v = make_float4(0.f, 0.f, 0.f, 0.f);
            if (row < M) v = *(const float4*)(A + (size_t)row * K + k0 + k4);
            As[k4 + 0][r] = v.x; As[k4 + 1][r] = v.y;
            As[k4 + 2][r] = v.z; As[k4 + 3][r] = v.w;
        }
        {
            int kb = tid >> 4;
            int c4 = (tid & 15) * 4;
            float4 v = *(const float4*)(B + (size_t)(k0 + kb) * N + colBase + c4);
            *(float4*)&Bs[kb][c4] = v;
        }
        __syncthreads();
        #pragma unroll
        for (int kk = 0; kk < 16; kk++) {
            float a[4], b[4];
            #pragma unroll
            for (int i = 0; i < 4; i++) a[i] = As[kk][tr * 4 + i];
            #pragma unroll
            for (int j = 0; j < 4; j++) b[j] = Bs[kk][tc * 4 + j];
            #pragma unroll
            for (int i = 0; i < 4; i++)
                #pragma unroll
                for (int j = 0; j < 4; j++)
                    acc[i][j] = fmaf(a[i], b[j], acc[i][j]);
        }
        __syncthreads();
    }
    #pragma unroll
    for (int i = 0; i < 4; i++) {
        int row = rowBase + tr * 4 + i;
        if (row < M) {
            float4 v = make_float4(acc[i][0], acc[i][1], acc[i][2], acc[i][3]);
            *(float4*)(C + (size_t)row * N + colBase + tc * 4) = v;
        }
    }
}

// ---------- layer-1 attention: per-node softmax over incoming edges + aggregate ----------
// block = 256 threads = 4 waves; one block per destination node.
__global__ __launch_bounds__(256) void attn_l1(
    const float* __restrict__ xl, const float* __restrict__ xr,
    const float* __restrict__ att, const float* __restrict__ b1,
    const int* __restrict__ row_ptr, const int* __restrict__ csr_src,
    float* __restrict__ alpha, float* __restrict__ h1) {
    int d = blockIdx.x;
    int tid = threadIdx.x;
    int start = row_ptr[d], deg = row_ptr[d + 1] - start;

    __shared__ float s_xr[D1];
    __shared__ float s_att[D1];
    __shared__ unsigned s_maxu[HEADS];
    __shared__ float s_den[HEADS];

    s_xr[tid] = xr[(size_t)d * D1 + tid];
    s_xr[tid + 256] = xr[(size_t)d * D1 + 256 + tid];
    s_att[tid] = att[tid];
    s_att[tid + 256] = att[256 + tid];
    if (tid < HEADS) { s_maxu[tid] = fflip(-INFINITY); s_den[tid] = 0.f; }
    __syncthreads();

    if (deg > 0) {
        // pass A: per-edge scores. wave handles one edge; lane = h*8 + j, j sums 8 channels
        int wave = tid >> 6, lane = tid & 63;
        int h = lane >> 3, j = lane & 7;
        int coff = h * 64 + j * 8;
        for (int p = wave; p < deg; p += 4) {
            int s = csr_src[start + p];
            const float* xls = xl + (size_t)s * D1 + coff;
            float partial = 0.f;
            #pragma unroll
            for (int q = 0; q < 8; q++) {
                float v = xls[q] + s_xr[coff + q];
                v = v > 0.f ? v : NEG_SLOPE * v;
                partial = fmaf(s_att[coff + q], v, partial);
            }
            partial += __shfl_xor(partial, 1);
            partial += __shfl_xor(partial, 2);
            partial += __shfl_xor(partial, 4);
            if (j == 0) {
                alpha[(size_t)(start + p) * HEADS + h] = partial;
                atomicMax(&s_maxu[h], fflip(partial));
            }
        }
    }
    __syncthreads();
    if (deg > 0) {
        // pass B: exp + denom
        for (int idx = tid; idx < deg * HEADS; idx += 256) {
            int p = idx >> 3, h = idx & 7;
            float m = funflip(s_maxu[h]);
            float ex = __expf(alpha[(size_t)(start + p) * HEADS + h] - m);
            alpha[(size_t)(start + p) * HEADS + h] = ex;
            atomicAdd(&s_den[h], ex);
        }
    }
    __syncthreads();
    // pass C: aggregate. thread handles channels tid and tid+256.
    float acc0 = 0.f, acc1 = 0.f;
    int h0 = tid >> 6;
    int h1i = (tid + 256) >> 6;
    if (deg > 0) {
        for (int p = 0; p < deg; p++) {
            int s = csr_src[start + p];
            float w0 = alpha[(size_t)(start + p) * HEADS + h0];
            float w1 = alpha[(size_t)(start + p) * HEADS + h1i];
            acc0 = fmaf(w0, xl[(size_t)s * D1 + tid], acc0);
            acc1 = fmaf(w1, xl[(size_t)s * D1 + 256 + tid], acc1);
        }
        acc0 *= 1.f / (s_den[h0] + 1e-16f);
        acc1 *= 1.f / (s_den[h1i] + 1e-16f);
    }
    float o0 = acc0 + b1[tid];
    float o1 = acc1 + b1[tid + 256];
    h1[(size_t)d * D1 + tid] = o0 > 0.f ? o0 : (__expf(o0) - 1.f);         // ELU
    h1[(size_t)d * D1 + 256 + tid] = o1 > 0.f ? o1 : (__expf(o1) - 1.f);
}

// ---------- layer-2 attention: 1 head, C=64; one wave per node ----------
__global__ __launch_bounds__(64) void attn_l2(
    const float* __restrict__ yl, const float* __restrict__ yr,
    const float* __restrict__ att2, const float* __restrict__ b2,
    const int* __restrict__ row_ptr, const int* __restrict__ csr_src,
    float* __restrict__ alpha2, float* __restrict__ out) {
    int d = blockIdx.x;
    int lane = threadIdx.x;
    int start = row_ptr[d], deg = row_ptr[d + 1] - start;

    float yrv = yr[(size_t)d * NCLS + lane];
    float attv = att2[lane];
    float m = -INFINITY;
    // pass A: score per edge (lockstep over edges, full-wave reduce)
    for (int p = 0; p < deg; p++) {
        int s = csr_src[start + p];
        float v = yl[(size_t)s * NCLS + lane] + yrv;
        v = v > 0.f ? v : NEG_SLOPE * v;
        float a = attv * v;
        #pragma unroll
        for (int mask = 1; mask < 64; mask <<= 1) a += __shfl_xor(a, mask);
        if (lane == 0) alpha2[start + p] = a;
        m = fmaxf(m, a);
    }
    // pass B: exp + denom
    float den = 0.f;
    for (int p = lane; p < deg; p += 64) {
        float ex = __expf(alpha2[start + p] - m);
        alpha2[start + p] = ex;
        den += ex;
    }
    #pragma unroll
    for (int mask = 1; mask < 64; mask <<= 1) den += __shfl_xor(den, mask);
    float inv = 1.f / (den + 1e-16f);
    // pass C: aggregate
    float acc = 0.f;
    for (int p = 0; p < deg; p++) {
        int s = csr_src[start + p];
        float w = alpha2[start + p];
        acc = fmaf(w, yl[(size_t)s * NCLS + lane], acc);
    }
    out[(size_t)d * NCLS + lane] = acc * inv + b2[lane];
}

extern "C" void kernel_launch(void* const* d_in, const int* in_sizes, int n_in,
                              void* d_out, int out_size, void* d_ws, size_t ws_size,
                              hipStream_t stream) {
    const float* x    = (const float*)d_in[0];
    const int*   edge = (const int*)d_in[1];
    const float* Wl1  = (const float*)d_in[2];
    const float* Wr1  = (const float*)d_in[3];
    const float* att1 = (const float*)d_in[4];
    const float* b1   = (const float*)d_in[5];
    const float* Wl2  = (const float*)d_in[6];
    const float* Wr2  = (const float*)d_in[7];
    const float* att2 = (const float*)d_in[8];
    const float* b2   = (const float*)d_in[9];
    float* out = (float*)d_out;

    const int* srcv = edge;
    const int* dstv = edge + N_EDGES;

    float* xl1   = (float*)d_ws;                         // N*512
    float* xr1   = xl1 + (size_t)N_NODES * D1;           // N*512
    float* h1    = xr1 + (size_t)N_NODES * D1;           // N*512
    float* yl    = h1 + (size_t)N_NODES * D1;            // N*64
    float* yr    = yl + (size_t)N_NODES * NCLS;          // N*64
    float* alpha = yr + (size_t)N_NODES * NCLS;          // E*8
    int* cnt     = (int*)(alpha + (size_t)N_EDGES * HEADS);
    int* row_ptr = cnt + N_NODES;                        // N+1
    int* cursor  = row_ptr + N_NODES + 1;                // N
    int* csr_src = cursor + N_NODES;                     // E

    hipMemsetAsync(cnt, 0, N_NODES * sizeof(int), stream);
    hist_kernel<<<N_EDGES / 256, 256, 0, stream>>>(dstv, cnt, N_EDGES);
    scan_kernel<<<1, 256, 0, stream>>>(cnt, row_ptr, cursor, N_NODES);
    scatter_kernel<<<N_EDGES / 256, 256, 0, stream>>>(srcv, dstv, cursor, csr_src, N_EDGES);

    // layer 1 projections
    gemm_tile<<<dim3(D1 / 64, (N_NODES + 63) / 64), 256, 0, stream>>>(x, Wl1, xl1, N_NODES, D1, F_IN);
    gemm_tile<<<dim3(D1 / 64, (N_NODES + 63) / 64), 256, 0, stream>>>(x, Wr1, xr1, N_NODES, D1, F_IN);
    // layer 1 attention + aggregate + bias + ELU
    attn_l1<<<N_NODES, 256, 0, stream>>>(xl1, xr1, att1, b1, row_ptr, csr_src, alpha, h1);
    // layer 2 projections
    gemm_tile<<<dim3(NCLS / 64, (N_NODES + 63) / 64), 256, 0, stream>>>(h1, Wl2, yl, N_NODES, NCLS, D1);
    gemm_tile<<<dim3(NCLS / 64, (N_NODES + 63) / 64), 256, 0, stream>>>(h1, Wr2, yr, N_NODES, NCLS, D1);
    // layer 2 attention + aggregate + bias
    attn_l2<<<N_NODES, 64, 0, stream>>>(yl, yr, att2, b2, row_ptr, csr_src, alpha, out);
}

// Round 2
// 573.577 us; speedup vs baseline: 1.1122x; 1.1122x over previous
//
#include <hip/hip_runtime.h>
#include <hip/hip_bf16.h>

#define N_NODES 20000
#define N_EDGES 320000
#define F_IN 256
#define HID 64
#define HEADS 8
#define NCLS 64
#define D1 (HEADS * HID)   // 512
#define NEG_SLOPE 0.2f
#define SCAN_BLOCKS ((N_NODES + 255) / 256)   // 79

// ---------- CSR build ----------
__global__ void hist_kernel(const int* __restrict__ dst, int* __restrict__ cnt, int E) {
    int i = blockIdx.x * 256 + threadIdx.x;
    if (i < E) atomicAdd(&cnt[dst[i]], 1);
}

// hierarchical scan: per-block inclusive scan via wave shuffles
__global__ __launch_bounds__(256) void scan_local(const int* __restrict__ cnt,
                                                  int* __restrict__ pscan,
                                                  int* __restrict__ bsum, int n) {
    int tid = threadIdx.x;
    int i = blockIdx.x * 256 + tid;
    int lane = tid & 63, wave = tid >> 6;
    int v = (i < n) ? cnt[i] : 0;
    int x = v;
    #pragma unroll
    for (int d = 1; d < 64; d <<= 1) {
        int y = __shfl_up(x, d);
        if (lane >= d) x += y;
    }
    __shared__ int wsum[4];
    if (lane == 63) wsum[wave] = x;
    __syncthreads();
    int woff = 0;
    for (int w2 = 0; w2 < wave; w2++) woff += wsum[w2];
    int incl = x + woff;
    if (i < n) pscan[i] = incl;
    if (tid == 255) bsum[blockIdx.x] = incl;
}

__global__ __launch_bounds__(128) void scan_block(int* __restrict__ bsum, int nb) {
    int tid = threadIdx.x;
    __shared__ int sh[128];
    int v = (tid < nb) ? bsum[tid] : 0;
    sh[tid] = v;
    __syncthreads();
    #pragma unroll
    for (int d = 1; d < 128; d <<= 1) {
        int x = (tid >= d) ? sh[tid - d] : 0;
        __syncthreads();
        sh[tid] += x;
        __syncthreads();
    }
    if (tid < nb) bsum[tid] = sh[tid] - v;   // exclusive block offsets
}

__global__ __launch_bounds__(256) void scan_finalize(const int* __restrict__ cnt,
                                                     const int* __restrict__ pscan,
                                                     const int* __restrict__ bsum,
                                                     int* __restrict__ row_ptr,
                                                     int* __restrict__ cursor, int n) {
    int i = blockIdx.x * 256 + threadIdx.x;
    if (i < n) {
        int incl = pscan[i] + bsum[blockIdx.x];
        row_ptr[i + 1] = incl;
        cursor[i] = incl - cnt[i];
    }
    if (i == 0) row_ptr[0] = 0;
}

__global__ void scatter_kernel(const int* __restrict__ src, const int* __restrict__ dst,
                               int* __restrict__ cursor, int* __restrict__ csr_src, int E) {
    int i = blockIdx.x * 256 + threadIdx.x;
    if (i < E) {
        int d = dst[i];
        int pos = atomicAdd(&cursor[d], 1);
        csr_src[pos] = src[i];
    }
}

// ---------- fp32 tiled GEMM: C[M,N] = A[M,K] @ B[K,N] ----------
__global__ __launch_bounds__(256) void gemm_tile(
    const float* __restrict__ A, const float* __restrict__ B, float* __restrict__ C,
    int M, int N, int K) {
    __shared__ float As[16][68];
    __shared__ float Bs[16][64];
    int tid = threadIdx.x;
    int rowBase = blockIdx.y * 64;
    int colBase = blockIdx.x * 64;
    int tr = tid >> 4, tc = tid & 15;
    float acc[4][4] = {};
    for (int k0 = 0; k0 < K; k0 += 16) {
        {
            int r = tid >> 2;
            int k4 = (tid & 3) * 4;
            int row = rowBase + r;
            float4 v = make_float4(0.f, 0.f, 0.f, 0.f);
            if (row < M) v = *(const float4*)(A + (size_t)row * K + k0 + k4);
            As[k4 + 0][r] = v.x; As[k4 + 1][r] = v.y;
            As[k4 + 2][r] = v.z; As[k4 + 3][r] = v.w;
        }
        {
            int kb = tid >> 4;
            int c4 = (tid & 15) * 4;
            float4 v = *(const float4*)(B + (size_t)(k0 + kb) * N + colBase + c4);
            *(float4*)&Bs[kb][c4] = v;
        }
        __syncthreads();
        #pragma unroll
        for (int kk = 0; kk < 16; kk++) {
            float a[4], b[4];
            #pragma unroll
            for (int i = 0; i < 4; i++) a[i] = As[kk][tr * 4 + i];
            #pragma unroll
            for (int j = 0; j < 4; j++) b[j] = Bs[kk][tc * 4 + j];
            #pragma unroll
            for (int i = 0; i < 4; i++)
                #pragma unroll
                for (int j = 0; j < 4; j++)
                    acc[i][j] = fmaf(a[i], b[j], acc[i][j]);
        }
        __syncthreads();
    }
    #pragma unroll
    for (int i = 0; i < 4; i++) {
        int row = rowBase + tr * 4 + i;
        if (row < M) {
            float4 v = make_float4(acc[i][0], acc[i][1], acc[i][2], acc[i][3]);
            *(float4*)(C + (size_t)row * N + colBase + tc * 4) = v;
        }
    }
}

// ---------- layer-1 fused attention: single-gather online softmax ----------
// block = 256 threads, one dst node. thread tid holds channels tid (head tid>>6)
// and tid+256 (head (tid>>6)+4); lanes 0..63 of wave w hold head w's 64 channels,
// so per-head scores reduce with 64-lane shuffles over already-loaded values.
__global__ __launch_bounds__(256) void attn_l1_fused(
    const float* __restrict__ xl, const float* __restrict__ xr,
    const float* __restrict__ att, const float* __restrict__ b1,
    const int* __restrict__ row_ptr, const int* __restrict__ csr_src,
    float* __restrict__ h1out) {
    int d = blockIdx.x, tid = threadIdx.x;
    int start = row_ptr[d], deg = row_ptr[d + 1] - start;

    float xr0 = xr[(size_t)d * D1 + tid];
    float xr1v = xr[(size_t)d * D1 + 256 + tid];
    float at0 = att[tid];
    float at1 = att[256 + tid];

    float m0 = -INFINITY, m1 = -INFINITY;
    float den0 = 0.f, den1 = 0.f, acc0 = 0.f, acc1 = 0.f;

    for (int p = 0; p < deg; p++) {
        int s = csr_src[start + p];                 // wave-uniform broadcast load
        const float* xp = xl + (size_t)s * D1;
        float xv0 = xp[tid];
        float xv1 = xp[256 + tid];
        float v0 = xv0 + xr0; v0 = v0 > 0.f ? v0 : NEG_SLOPE * v0;
        float v1 = xv1 + xr1v; v1 = v1 > 0.f ? v1 : NEG_SLOPE * v1;
        float p0 = at0 * v0, p1 = at1 * v1;
        #pragma unroll
        for (int mask = 1; mask < 64; mask <<= 1) {
            p0 += __shfl_xor(p0, mask);
            p1 += __shfl_xor(p1, mask);
        }
        // online softmax update (m=-inf safe: exp(-inf)=0 on first edge)
        float mn0 = fmaxf(m0, p0), mn1 = fmaxf(m1, p1);
        float c0 = __expf(m0 - mn0), c1 = __expf(m1 - mn1);
        float e0 = __expf(p0 - mn0), e1 = __expf(p1 - mn1);
        den0 = den0 * c0 + e0;  den1 = den1 * c1 + e1;
        acc0 = acc0 * c0 + e0 * xv0;
        acc1 = acc1 * c1 + e1 * xv1;
        m0 = mn0; m1 = mn1;
    }
    float o0 = acc0 / (den0 + 1e-16f) + b1[tid];
    float o1 = acc1 / (den1 + 1e-16f) + b1[256 + tid];
    h1out[(size_t)d * D1 + tid] = o0 > 0.f ? o0 : (__expf(o0) - 1.f);       // ELU
    h1out[(size_t)d * D1 + 256 + tid] = o1 > 0.f ? o1 : (__expf(o1) - 1.f);
}

// ---------- layer-2 fused attention: 1 head, C=64; one wave per node ----------
__global__ __launch_bounds__(256) void attn_l2_fused(
    const float* __restrict__ yl, const float* __restrict__ yr,
    const float* __restrict__ att2, const float* __restrict__ b2,
    const int* __restrict__ row_ptr, const int* __restrict__ csr_src,
    float* __restrict__ out) {
    int wave = threadIdx.x >> 6, lane = threadIdx.x & 63;
    int d = blockIdx.x * 4 + wave;
    if (d >= N_NODES) return;
    int start = row_ptr[d], deg = row_ptr[d + 1] - start;

    float yrv = yr[(size_t)d * NCLS + lane];
    float attv = att2[lane];
    float m = -INFINITY, den = 0.f, acc = 0.f;

    for (int p = 0; p < deg; p++) {
        int s = csr_src[start + p];
        float yv = yl[(size_t)s * NCLS + lane];
        float v = yv + yrv; v = v > 0.f ? v : NEG_SLOPE * v;
        float a = attv * v;
        #pragma unroll
        for (int mask = 1; mask < 64; mask <<= 1) a += __shfl_xor(a, mask);
        float mn = fmaxf(m, a);
        float c = __expf(m - mn), e = __expf(a - mn);
        den = den * c + e;
        acc = acc * c + e * yv;
        m = mn;
    }
    out[(size_t)d * NCLS + lane] = acc / (den + 1e-16f) + b2[lane];
}

extern "C" void kernel_launch(void* const* d_in, const int* in_sizes, int n_in,
                              void* d_out, int out_size, void* d_ws, size_t ws_size,
                              hipStream_t stream) {
    const float* x    = (const float*)d_in[0];
    const int*   edge = (const int*)d_in[1];
    const float* Wl1  = (const float*)d_in[2];
    const float* Wr1  = (const float*)d_in[3];
    const float* att1 = (const float*)d_in[4];
    const float* b1   = (const float*)d_in[5];
    const float* Wl2  = (const float*)d_in[6];
    const float* Wr2  = (const float*)d_in[7];
    const float* att2 = (const float*)d_in[8];
    const float* b2   = (const float*)d_in[9];
    float* out = (float*)d_out;

    const int* srcv = edge;
    const int* dstv = edge + N_EDGES;

    float* xl1   = (float*)d_ws;                         // N*512
    float* xr1   = xl1 + (size_t)N_NODES * D1;           // N*512
    float* h1    = xr1 + (size_t)N_NODES * D1;           // N*512
    float* yl    = h1 + (size_t)N_NODES * D1;            // N*64
    float* yr    = yl + (size_t)N_NODES * NCLS;          // N*64
    int* cnt     = (int*)(yr + (size_t)N_NODES * NCLS);  // N
    int* pscan   = cnt + N_NODES;                        // N
    int* bsum    = pscan + N_NODES;                      // 128
    int* row_ptr = bsum + 128;                           // N+1
    int* cursor  = row_ptr + N_NODES + 1;                // N
    int* csr_src = cursor + N_NODES;                     // E

    hipMemsetAsync(cnt, 0, N_NODES * sizeof(int), stream);
    hist_kernel<<<N_EDGES / 256, 256, 0, stream>>>(dstv, cnt, N_EDGES);
    scan_local<<<SCAN_BLOCKS, 256, 0, stream>>>(cnt, pscan, bsum, N_NODES);
    scan_block<<<1, 128, 0, stream>>>(bsum, SCAN_BLOCKS);
    scan_finalize<<<SCAN_BLOCKS, 256, 0, stream>>>(cnt, pscan, bsum, row_ptr, cursor, N_NODES);
    scatter_kernel<<<N_EDGES / 256, 256, 0, stream>>>(srcv, dstv, cursor, csr_src, N_EDGES);

    // layer 1 projections
    gemm_tile<<<dim3(D1 / 64, (N_NODES + 63) / 64), 256, 0, stream>>>(x, Wl1, xl1, N_NODES, D1, F_IN);
    gemm_tile<<<dim3(D1 / 64, (N_NODES + 63) / 64), 256, 0, stream>>>(x, Wr1, xr1, N_NODES, D1, F_IN);
    // layer 1 fused attention + bias + ELU
    attn_l1_fused<<<N_NODES, 256, 0, stream>>>(xl1, xr1, att1, b1, row_ptr, csr_src, h1);
    // layer 2 projections
    gemm_tile<<<dim3(NCLS / 64, (N_NODES + 63) / 64), 256, 0, stream>>>(h1, Wl2, yl, N_NODES, NCLS, D1);
    gemm_tile<<<dim3(NCLS / 64, (N_NODES + 63) / 64), 256, 0, stream>>>(h1, Wr2, yr, N_NODES, NCLS, D1);
    // layer 2 fused attention + bias
    attn_l2_fused<<<(N_NODES + 3) / 4, 256, 0, stream>>>(yl, yr, att2, b2, row_ptr, csr_src, out);
}

// Round 3
// 511.227 us; speedup vs baseline: 1.2479x; 1.1220x over previous
//
#include <hip/hip_runtime.h>
#include <hip/hip_bf16.h>

#define N_NODES 20000
#define N_EDGES 320000
#define F_IN 256
#define HID 64
#define HEADS 8
#define NCLS 64
#define D1 (HEADS * HID)   // 512
#define NEG_SLOPE 0.2f
#define SCAN_BLOCKS ((N_NODES + 255) / 256)   // 79

// ---------- CSR build ----------
__global__ void hist_kernel(const int* __restrict__ dst, int* __restrict__ cnt, int E) {
    int i = blockIdx.x * 256 + threadIdx.x;
    if (i < E) atomicAdd(&cnt[dst[i]], 1);
}

__global__ __launch_bounds__(256) void scan_local(const int* __restrict__ cnt,
                                                  int* __restrict__ pscan,
                                                  int* __restrict__ bsum, int n) {
    int tid = threadIdx.x;
    int i = blockIdx.x * 256 + tid;
    int lane = tid & 63, wave = tid >> 6;
    int v = (i < n) ? cnt[i] : 0;
    int x = v;
    #pragma unroll
    for (int d = 1; d < 64; d <<= 1) {
        int y = __shfl_up(x, d);
        if (lane >= d) x += y;
    }
    __shared__ int wsum[4];
    if (lane == 63) wsum[wave] = x;
    __syncthreads();
    int woff = 0;
    for (int w2 = 0; w2 < wave; w2++) woff += wsum[w2];
    int incl = x + woff;
    if (i < n) pscan[i] = incl;
    if (tid == 255) bsum[blockIdx.x] = incl;
}

__global__ __launch_bounds__(128) void scan_block(int* __restrict__ bsum, int nb) {
    int tid = threadIdx.x;
    __shared__ int sh[128];
    int v = (tid < nb) ? bsum[tid] : 0;
    sh[tid] = v;
    __syncthreads();
    #pragma unroll
    for (int d = 1; d < 128; d <<= 1) {
        int x = (tid >= d) ? sh[tid - d] : 0;
        __syncthreads();
        sh[tid] += x;
        __syncthreads();
    }
    if (tid < nb) bsum[tid] = sh[tid] - v;   // exclusive block offsets
}

__global__ __launch_bounds__(256) void scan_finalize(const int* __restrict__ cnt,
                                                     const int* __restrict__ pscan,
                                                     const int* __restrict__ bsum,
                                                     int* __restrict__ row_ptr,
                                                     int* __restrict__ cursor, int n) {
    int i = blockIdx.x * 256 + threadIdx.x;
    if (i < n) {
        int incl = pscan[i] + bsum[blockIdx.x];
        row_ptr[i + 1] = incl;
        cursor[i] = incl - cnt[i];
    }
    if (i == 0) row_ptr[0] = 0;
}

__global__ void scatter_kernel(const int* __restrict__ src, const int* __restrict__ dst,
                               int* __restrict__ cursor, int* __restrict__ csr_src, int E) {
    int i = blockIdx.x * 256 + threadIdx.x;
    if (i < E) {
        int d = dst[i];
        int pos = atomicAdd(&cursor[d], 1);
        csr_src[pos] = src[i];
    }
}

// ---------- fp32 tiled GEMM: C[M,N] = A[M,K] @ B[K,N] ----------
__global__ __launch_bounds__(256) void gemm_tile(
    const float* __restrict__ A, const float* __restrict__ B, float* __restrict__ C,
    int M, int N, int K) {
    __shared__ float As[16][68];
    __shared__ float Bs[16][64];
    int tid = threadIdx.x;
    int rowBase = blockIdx.y * 64;
    int colBase = blockIdx.x * 64;
    int tr = tid >> 4, tc = tid & 15;
    float acc[4][4] = {};
    for (int k0 = 0; k0 < K; k0 += 16) {
        {
            int r = tid >> 2;
            int k4 = (tid & 3) * 4;
            int row = rowBase + r;
            float4 v = make_float4(0.f, 0.f, 0.f, 0.f);
            if (row < M) v = *(const float4*)(A + (size_t)row * K + k0 + k4);
            As[k4 + 0][r] = v.x; As[k4 + 1][r] = v.y;
            As[k4 + 2][r] = v.z; As[k4 + 3][r] = v.w;
        }
        {
            int kb = tid >> 4;
            int c4 = (tid & 15) * 4;
            float4 v = *(const float4*)(B + (size_t)(k0 + kb) * N + colBase + c4);
            *(float4*)&Bs[kb][c4] = v;
        }
        __syncthreads();
        #pragma unroll
        for (int kk = 0; kk < 16; kk++) {
            float a[4], b[4];
            #pragma unroll
            for (int i = 0; i < 4; i++) a[i] = As[kk][tr * 4 + i];
            #pragma unroll
            for (int j = 0; j < 4; j++) b[j] = Bs[kk][tc * 4 + j];
            #pragma unroll
            for (int i = 0; i < 4; i++)
                #pragma unroll
                for (int j = 0; j < 4; j++)
                    acc[i][j] = fmaf(a[i], b[j], acc[i][j]);
        }
        __syncthreads();
    }
    #pragma unroll
    for (int i = 0; i < 4; i++) {
        int row = rowBase + tr * 4 + i;
        if (row < M) {
            float4 v = make_float4(acc[i][0], acc[i][1], acc[i][2], acc[i][3]);
            *(float4*)(C + (size_t)row * N + colBase + tc * 4) = v;
        }
    }
}

// ---------- layer-1 fused attention: single-gather, no-max softmax ----------
// block = 256 threads, one dst node. thread tid owns channels 2tid, 2tid+1
// (same head: head = tid>>5 within wave halves). Per-edge score = 5-step
// butterfly within 32-lane halves; each half ends with its own head's sum.
__global__ __launch_bounds__(256) void attn_l1_fused(
    const float* __restrict__ xl, const float* __restrict__ xr,
    const float* __restrict__ att, const float* __restrict__ b1,
    const int* __restrict__ row_ptr, const int* __restrict__ csr_src,
    float* __restrict__ h1out) {
    int d = blockIdx.x, tid = threadIdx.x;
    int start = row_ptr[d], deg = row_ptr[d + 1] - start;

    float2 xrv = *(const float2*)(xr + (size_t)d * D1 + 2 * tid);
    float2 atv = *(const float2*)(att + 2 * tid);

    float den = 0.f;
    float accx = 0.f, accy = 0.f;

    if (deg > 0) {
        int s = csr_src[start];
        float2 xv = *(const float2*)(xl + (size_t)s * D1 + 2 * tid);
        for (int p = 0; p < deg; p++) {
            float2 cur = xv;
            if (p + 1 < deg) {                      // prefetch next edge's row
                int sn = csr_src[start + p + 1];
                xv = *(const float2*)(xl + (size_t)sn * D1 + 2 * tid);
            }
            float v0 = cur.x + xrv.x; v0 = v0 > 0.f ? v0 : NEG_SLOPE * v0;
            float v1 = cur.y + xrv.y; v1 = v1 > 0.f ? v1 : NEG_SLOPE * v1;
            float pv = fmaf(atv.x, v0, atv.y * v1);
            #pragma unroll
            for (int mask = 1; mask < 32; mask <<= 1) pv += __shfl_xor(pv, mask);
            float e = __expf(pv);                   // no max subtraction: scores bounded
            den += e;
            accx = fmaf(e, cur.x, accx);
            accy = fmaf(e, cur.y, accy);
        }
    }
    float inv = 1.f / (den + 1e-16f);
    float2 bv = *(const float2*)(b1 + 2 * tid);
    float o0 = accx * inv + bv.x;
    float o1 = accy * inv + bv.y;
    float2 ov;
    ov.x = o0 > 0.f ? o0 : (__expf(o0) - 1.f);     // ELU
    ov.y = o1 > 0.f ? o1 : (__expf(o1) - 1.f);
    *(float2*)(h1out + (size_t)d * D1 + 2 * tid) = ov;
}

// ---------- layer-2 fused attention: 1 head, C=64; one wave per node ----------
__global__ __launch_bounds__(256) void attn_l2_fused(
    const float* __restrict__ yl, const float* __restrict__ yr,
    const float* __restrict__ att2, const float* __restrict__ b2,
    const int* __restrict__ row_ptr, const int* __restrict__ csr_src,
    float* __restrict__ out) {
    int wave = threadIdx.x >> 6, lane = threadIdx.x & 63;
    int d = blockIdx.x * 4 + wave;
    if (d >= N_NODES) return;
    int start = row_ptr[d], deg = row_ptr[d + 1] - start;

    float yrv = yr[(size_t)d * NCLS + lane];
    float attv = att2[lane];
    float den = 0.f, acc = 0.f;

    if (deg > 0) {
        int s = csr_src[start];
        float yv = yl[(size_t)s * NCLS + lane];
        for (int p = 0; p < deg; p++) {
            float cur = yv;
            if (p + 1 < deg) {
                int sn = csr_src[start + p + 1];
                yv = yl[(size_t)sn * NCLS + lane];
            }
            float v = cur + yrv; v = v > 0.f ? v : NEG_SLOPE * v;
            float a = attv * v;
            #pragma unroll
            for (int mask = 1; mask < 64; mask <<= 1) a += __shfl_xor(a, mask);
            float e = __expf(a);
            den += e;
            acc = fmaf(e, cur, acc);
        }
    }
    out[(size_t)d * NCLS + lane] = acc / (den + 1e-16f) + b2[lane];
}

extern "C" void kernel_launch(void* const* d_in, const int* in_sizes, int n_in,
                              void* d_out, int out_size, void* d_ws, size_t ws_size,
                              hipStream_t stream) {
    const float* x    = (const float*)d_in[0];
    const int*   edge = (const int*)d_in[1];
    const float* Wl1  = (const float*)d_in[2];
    const float* Wr1  = (const float*)d_in[3];
    const float* att1 = (const float*)d_in[4];
    const float* b1   = (const float*)d_in[5];
    const float* Wl2  = (const float*)d_in[6];
    const float* Wr2  = (const float*)d_in[7];
    const float* att2 = (const float*)d_in[8];
    const float* b2   = (const float*)d_in[9];
    float* out = (float*)d_out;

    const int* srcv = edge;
    const int* dstv = edge + N_EDGES;

    float* xl1   = (float*)d_ws;                         // N*512
    float* xr1   = xl1 + (size_t)N_NODES * D1;           // N*512
    float* h1    = xr1 + (size_t)N_NODES * D1;           // N*512
    float* yl    = h1 + (size_t)N_NODES * D1;            // N*64
    float* yr    = yl + (size_t)N_NODES * NCLS;          // N*64
    int* cnt     = (int*)(yr + (size_t)N_NODES * NCLS);  // N
    int* pscan   = cnt + N_NODES;                        // N
    int* bsum    = pscan + N_NODES;                      // 128
    int* row_ptr = bsum + 128;                           // N+1
    int* cursor  = row_ptr + N_NODES + 1;                // N
    int* csr_src = cursor + N_NODES;                     // E

    hipMemsetAsync(cnt, 0, N_NODES * sizeof(int), stream);
    hist_kernel<<<N_EDGES / 256, 256, 0, stream>>>(dstv, cnt, N_EDGES);
    scan_local<<<SCAN_BLOCKS, 256, 0, stream>>>(cnt, pscan, bsum, N_NODES);
    scan_block<<<1, 128, 0, stream>>>(bsum, SCAN_BLOCKS);
    scan_finalize<<<SCAN_BLOCKS, 256, 0, stream>>>(cnt, pscan, bsum, row_ptr, cursor, N_NODES);
    scatter_kernel<<<N_EDGES / 256, 256, 0, stream>>>(srcv, dstv, cursor, csr_src, N_EDGES);

    // layer 1 projections
    gemm_tile<<<dim3(D1 / 64, (N_NODES + 63) / 64), 256, 0, stream>>>(x, Wl1, xl1, N_NODES, D1, F_IN);
    gemm_tile<<<dim3(D1 / 64, (N_NODES + 63) / 64), 256, 0, stream>>>(x, Wr1, xr1, N_NODES, D1, F_IN);
    // layer 1 fused attention + bias + ELU
    attn_l1_fused<<<N_NODES, 256, 0, stream>>>(xl1, xr1, att1, b1, row_ptr, csr_src, h1);
    // layer 2 projections
    gemm_tile<<<dim3(NCLS / 64, (N_NODES + 63) / 64), 256, 0, stream>>>(h1, Wl2, yl, N_NODES, NCLS, D1);
    gemm_tile<<<dim3(NCLS / 64, (N_NODES + 63) / 64), 256, 0, stream>>>(h1, Wr2, yr, N_NODES, NCLS, D1);
    // layer 2 fused attention + bias
    attn_l2_fused<<<(N_NODES + 3) / 4, 256, 0, stream>>>(yl, yr, att2, b2, row_ptr, csr_src, out);
}

// Round 4
// 328.471 us; speedup vs baseline: 1.9422x; 1.5564x over previous
//
#include <hip/hip_runtime.h>
#include <hip/hip_bf16.h>

#define N_NODES 20000
#define N_EDGES 320000
#define F_IN 256
#define HID 64
#define HEADS 8
#define NCLS 64
#define D1 (HEADS * HID)   // 512
#define NEG_SLOPE 0.2f
#define SCAN_BLOCKS ((N_NODES + 255) / 256)   // 79

typedef __attribute__((ext_vector_type(8))) short short8;
typedef __attribute__((ext_vector_type(4))) float floatx4;

__device__ __forceinline__ ushort f2bf(float f) {
    unsigned u = __float_as_uint(f);
    unsigned r = (u + 0x7fffu + ((u >> 16) & 1u)) >> 16;
    return (ushort)r;
}

// ---------- conversions ----------
__global__ __launch_bounds__(256) void convert_bf16_vec(const float* __restrict__ in,
                                                        ushort* __restrict__ out, int n4) {
    int i = blockIdx.x * 256 + threadIdx.x;
    if (i < n4) {
        float4 v = ((const float4*)in)[i];
        ushort4 o;
        o.x = f2bf(v.x); o.y = f2bf(v.y); o.z = f2bf(v.z); o.w = f2bf(v.w);
        ((ushort4*)out)[i] = o;
    }
}

// W [Kd][Nd] fp32 -> Wt [Nd][Kd] bf16 (Kd = 1<<kshift)
__global__ __launch_bounds__(256) void transpose_w_bf16(const float* __restrict__ W,
                                                        ushort* __restrict__ Wt,
                                                        int kshift, int Nd, int total) {
    int i = blockIdx.x * 256 + threadIdx.x;
    if (i < total) {
        int n = i >> kshift, k = i & ((1 << kshift) - 1);
        Wt[i] = f2bf(W[(size_t)k * Nd + n]);
    }
}

// ---------- CSR build ----------
__global__ void hist_kernel(const int* __restrict__ dst, int* __restrict__ cnt, int E) {
    int i = blockIdx.x * 256 + threadIdx.x;
    if (i < E) atomicAdd(&cnt[dst[i]], 1);
}

__global__ __launch_bounds__(256) void scan_local(const int* __restrict__ cnt,
                                                  int* __restrict__ pscan,
                                                  int* __restrict__ bsum, int n) {
    int tid = threadIdx.x;
    int i = blockIdx.x * 256 + tid;
    int lane = tid & 63, wave = tid >> 6;
    int v = (i < n) ? cnt[i] : 0;
    int x = v;
    #pragma unroll
    for (int d = 1; d < 64; d <<= 1) {
        int y = __shfl_up(x, d);
        if (lane >= d) x += y;
    }
    __shared__ int wsum[4];
    if (lane == 63) wsum[wave] = x;
    __syncthreads();
    int woff = 0;
    for (int w2 = 0; w2 < wave; w2++) woff += wsum[w2];
    int incl = x + woff;
    if (i < n) pscan[i] = incl;
    if (tid == 255) bsum[blockIdx.x] = incl;
}

__global__ __launch_bounds__(128) void scan_block(int* __restrict__ bsum, int nb) {
    int tid = threadIdx.x;
    __shared__ int sh[128];
    int v = (tid < nb) ? bsum[tid] : 0;
    sh[tid] = v;
    __syncthreads();
    #pragma unroll
    for (int d = 1; d < 128; d <<= 1) {
        int x = (tid >= d) ? sh[tid - d] : 0;
        __syncthreads();
        sh[tid] += x;
        __syncthreads();
    }
    if (tid < nb) bsum[tid] = sh[tid] - v;   // exclusive block offsets
}

__global__ __launch_bounds__(256) void scan_finalize(const int* __restrict__ cnt,
                                                     const int* __restrict__ pscan,
                                                     const int* __restrict__ bsum,
                                                     int* __restrict__ row_ptr,
                                                     int* __restrict__ cursor, int n) {
    int i = blockIdx.x * 256 + threadIdx.x;
    if (i < n) {
        int incl = pscan[i] + bsum[blockIdx.x];
        row_ptr[i + 1] = incl;
        cursor[i] = incl - cnt[i];
    }
    if (i == 0) row_ptr[0] = 0;
}

__global__ void scatter_kernel(const int* __restrict__ src, const int* __restrict__ dst,
                               int* __restrict__ cursor, int* __restrict__ csr_src, int E) {
    int i = blockIdx.x * 256 + threadIdx.x;
    if (i < E) {
        int d = dst[i];
        int pos = atomicAdd(&cursor[d], 1);
        csr_src[pos] = src[i];
    }
}

// ---------- bf16 MFMA GEMM: C[M,N] = A[M,K] @ Bt[N,K]^T ----------
// tile 128M x 64N, 256 threads (4 waves); wave w owns rows w*32..w*32+31.
// LDS rows padded to 40 bf16 (80 B, 16B-aligned) to break power-of-2 strides.
#define APAD 40
__global__ __launch_bounds__(256) void gemm_mfma_bt(
    const ushort* __restrict__ A, const ushort* __restrict__ Bt,
    float* __restrict__ C, int M, int N, int K) {
    __shared__ ushort As[128 * APAD];
    __shared__ ushort Bs[64 * APAD];
    int tid = threadIdx.x;
    int rowBase = blockIdx.y * 128, colBase = blockIdx.x * 64;
    int wave = tid >> 6, lane = tid & 63;
    int quad = lane >> 4, m16 = lane & 15;
    floatx4 acc[2][4];
    #pragma unroll
    for (int i = 0; i < 2; i++)
        #pragma unroll
        for (int j = 0; j < 4; j++) acc[i][j] = (floatx4){0.f, 0.f, 0.f, 0.f};

    for (int k0 = 0; k0 < K; k0 += 32) {
        // stage A tile: 128 rows x 32 k (8 KB) = 512 x 16B
        #pragma unroll
        for (int i = 0; i < 2; i++) {
            int idx = i * 256 + tid;
            int r = idx >> 2, kq = (idx & 3) * 8;
            int grow = rowBase + r;
            uint4 v = make_uint4(0, 0, 0, 0);
            if (grow < M) v = *(const uint4*)(A + (size_t)grow * K + k0 + kq);
            *(uint4*)&As[r * APAD + kq] = v;
        }
        // stage B tile: 64 rows x 32 k (4 KB) = 256 x 16B
        {
            int r = tid >> 2, kq = (tid & 3) * 8;
            uint4 v = *(const uint4*)(Bt + (size_t)(colBase + r) * K + k0 + kq);
            *(uint4*)&Bs[r * APAD + kq] = v;
        }
        __syncthreads();
        // A frag: lane holds A[m=m16][k=quad*8+j]; B frag: Bt row n=m16, k contiguous
        short8 a0 = *(short8*)&As[(wave * 32 + m16) * APAD + quad * 8];
        short8 a1 = *(short8*)&As[(wave * 32 + 16 + m16) * APAD + quad * 8];
        #pragma unroll
        for (int ct = 0; ct < 4; ct++) {
            short8 b = *(short8*)&Bs[(ct * 16 + m16) * APAD + quad * 8];
            acc[0][ct] = __builtin_amdgcn_mfma_f32_16x16x32_bf16(a0, b, acc[0][ct], 0, 0, 0);
            acc[1][ct] = __builtin_amdgcn_mfma_f32_16x16x32_bf16(a1, b, acc[1][ct], 0, 0, 0);
        }
        __syncthreads();
    }
    // epilogue: C/D layout col=lane&15, row=quad*4+reg
    #pragma unroll
    for (int rt = 0; rt < 2; rt++)
        #pragma unroll
        for (int ct = 0; ct < 4; ct++)
            #pragma unroll
            for (int r = 0; r < 4; r++) {
                int row = rowBase + wave * 32 + rt * 16 + quad * 4 + r;
                if (row < M) C[(size_t)row * N + colBase + ct * 16 + m16] = acc[rt][ct][r];
            }
}

// ---------- layer-1 fused attention: single gather, 4-deep pipeline ----------
__global__ __launch_bounds__(256) void attn_l1_fused(
    const float* __restrict__ xl, const float* __restrict__ xr,
    const float* __restrict__ att, const float* __restrict__ b1,
    const int* __restrict__ row_ptr, const int* __restrict__ csr_src,
    ushort* __restrict__ h1out) {
    int d = blockIdx.x, tid = threadIdx.x;
    int start = row_ptr[d], deg = row_ptr[d + 1] - start;

    float2 xrv = *(const float2*)(xr + (size_t)d * D1 + 2 * tid);
    float2 atv = *(const float2*)(att + 2 * tid);

    float den = 0.f, accx = 0.f, accy = 0.f;

    if (deg > 0) {
        float2 xv[4];
        #pragma unroll
        for (int j = 0; j < 4; j++) {
            int p = min(j, deg - 1);
            int s = csr_src[start + p];
            xv[j] = *(const float2*)(xl + (size_t)s * D1 + 2 * tid);
        }
        for (int p0 = 0; p0 < deg; p0 += 4) {
            float2 c0 = xv[0], c1 = xv[1], c2 = xv[2], c3 = xv[3];
            // prefetch next batch (4 outstanding loads)
            #pragma unroll
            for (int j = 0; j < 4; j++) {
                int p = p0 + 4 + j;
                if (p < deg) {
                    int s = csr_src[start + p];
                    xv[j] = *(const float2*)(xl + (size_t)s * D1 + 2 * tid);
                }
            }
            // 4 independent score chains
            float v0, v1;
            v0 = c0.x + xrv.x; v0 = v0 > 0.f ? v0 : NEG_SLOPE * v0;
            v1 = c0.y + xrv.y; v1 = v1 > 0.f ? v1 : NEG_SLOPE * v1;
            float p0v = fmaf(atv.x, v0, atv.y * v1);
            v0 = c1.x + xrv.x; v0 = v0 > 0.f ? v0 : NEG_SLOPE * v0;
            v1 = c1.y + xrv.y; v1 = v1 > 0.f ? v1 : NEG_SLOPE * v1;
            float p1v = fmaf(atv.x, v0, atv.y * v1);
            v0 = c2.x + xrv.x; v0 = v0 > 0.f ? v0 : NEG_SLOPE * v0;
            v1 = c2.y + xrv.y; v1 = v1 > 0.f ? v1 : NEG_SLOPE * v1;
            float p2v = fmaf(atv.x, v0, atv.y * v1);
            v0 = c3.x + xrv.x; v0 = v0 > 0.f ? v0 : NEG_SLOPE * v0;
            v1 = c3.y + xrv.y; v1 = v1 > 0.f ? v1 : NEG_SLOPE * v1;
            float p3v = fmaf(atv.x, v0, atv.y * v1);
            #pragma unroll
            for (int mask = 1; mask < 32; mask <<= 1) {
                p0v += __shfl_xor(p0v, mask);
                p1v += __shfl_xor(p1v, mask);
                p2v += __shfl_xor(p2v, mask);
                p3v += __shfl_xor(p3v, mask);
            }
            float e0 = (p0 + 0 < deg) ? __expf(p0v) : 0.f;
            float e1 = (p0 + 1 < deg) ? __expf(p1v) : 0.f;
            float e2 = (p0 + 2 < deg) ? __expf(p2v) : 0.f;
            float e3 = (p0 + 3 < deg) ? __expf(p3v) : 0.f;
            den += (e0 + e1) + (e2 + e3);
            accx = fmaf(e0, c0.x, fmaf(e1, c1.x, fmaf(e2, c2.x, fmaf(e3, c3.x, accx))));
            accy = fmaf(e0, c0.y, fmaf(e1, c1.y, fmaf(e2, c2.y, fmaf(e3, c3.y, accy))));
        }
    }
    float inv = 1.f / (den + 1e-16f);
    float2 bv = *(const float2*)(b1 + 2 * tid);
    float o0 = accx * inv + bv.x;
    float o1 = accy * inv + bv.y;
    o0 = o0 > 0.f ? o0 : (__expf(o0) - 1.f);   // ELU
    o1 = o1 > 0.f ? o1 : (__expf(o1) - 1.f);
    ushort2 hv; hv.x = f2bf(o0); hv.y = f2bf(o1);
    *(ushort2*)(h1out + (size_t)d * D1 + 2 * tid) = hv;
}

// ---------- layer-2 fused attention: 1 head, C=64; wave/node, 4-deep pipeline ----------
__global__ __launch_bounds__(256) void attn_l2_fused(
    const float* __restrict__ yl, const float* __restrict__ yr,
    const float* __restrict__ att2, const float* __restrict__ b2,
    const int* __restrict__ row_ptr, const int* __restrict__ csr_src,
    float* __restrict__ out) {
    int wave = threadIdx.x >> 6, lane = threadIdx.x & 63;
    int d = blockIdx.x * 4 + wave;
    if (d >= N_NODES) return;
    int start = row_ptr[d], deg = row_ptr[d + 1] - start;

    float yrv = yr[(size_t)d * NCLS + lane];
    float attv = att2[lane];
    float den = 0.f, acc = 0.f;

    if (deg > 0) {
        float yv[4];
        #pragma unroll
        for (int j = 0; j < 4; j++) {
            int p = min(j, deg - 1);
            int s = csr_src[start + p];
            yv[j] = yl[(size_t)s * NCLS + lane];
        }
        for (int p0 = 0; p0 < deg; p0 += 4) {
            float c0 = yv[0], c1 = yv[1], c2 = yv[2], c3 = yv[3];
            #pragma unroll
            for (int j = 0; j < 4; j++) {
                int p = p0 + 4 + j;
                if (p < deg) {
                    int s = csr_src[start + p];
                    yv[j] = yl[(size_t)s * NCLS + lane];
                }
            }
            float v;
            v = c0 + yrv; v = v > 0.f ? v : NEG_SLOPE * v; float a0 = attv * v;
            v = c1 + yrv; v = v > 0.f ? v : NEG_SLOPE * v; float a1 = attv * v;
            v = c2 + yrv; v = v > 0.f ? v : NEG_SLOPE * v; float a2 = attv * v;
            v = c3 + yrv; v = v > 0.f ? v : NEG_SLOPE * v; float a3 = attv * v;
            #pragma unroll
            for (int mask = 1; mask < 64; mask <<= 1) {
                a0 += __shfl_xor(a0, mask);
                a1 += __shfl_xor(a1, mask);
                a2 += __shfl_xor(a2, mask);
                a3 += __shfl_xor(a3, mask);
            }
            float e0 = (p0 + 0 < deg) ? __expf(a0) : 0.f;
            float e1 = (p0 + 1 < deg) ? __expf(a1) : 0.f;
            float e2 = (p0 + 2 < deg) ? __expf(a2) : 0.f;
            float e3 = (p0 + 3 < deg) ? __expf(a3) : 0.f;
            den += (e0 + e1) + (e2 + e3);
            acc = fmaf(e0, c0, fmaf(e1, c1, fmaf(e2, c2, fmaf(e3, c3, acc))));
        }
    }
    out[(size_t)d * NCLS + lane] = acc / (den + 1e-16f) + b2[lane];
}

extern "C" void kernel_launch(void* const* d_in, const int* in_sizes, int n_in,
                              void* d_out, int out_size, void* d_ws, size_t ws_size,
                              hipStream_t stream) {
    const float* x    = (const float*)d_in[0];
    const int*   edge = (const int*)d_in[1];
    const float* Wl1  = (const float*)d_in[2];
    const float* Wr1  = (const float*)d_in[3];
    const float* att1 = (const float*)d_in[4];
    const float* b1   = (const float*)d_in[5];
    const float* Wl2  = (const float*)d_in[6];
    const float* Wr2  = (const float*)d_in[7];
    const float* att2 = (const float*)d_in[8];
    const float* b2   = (const float*)d_in[9];
    float* out = (float*)d_out;

    const int* srcv = edge;
    const int* dstv = edge + N_EDGES;

    ushort* xbf  = (ushort*)d_ws;                        // N*256
    ushort* wt1l = xbf + (size_t)N_NODES * F_IN;         // 512*256
    ushort* wt1r = wt1l + D1 * F_IN;                     // 512*256
    ushort* wt2l = wt1r + D1 * F_IN;                     // 64*512
    ushort* wt2r = wt2l + NCLS * D1;                     // 64*512
    float* xl1   = (float*)(wt2r + NCLS * D1);           // N*512
    float* xr1   = xl1 + (size_t)N_NODES * D1;           // N*512
    ushort* h1   = (ushort*)(xr1 + (size_t)N_NODES * D1);// N*512 bf16
    float* yl    = (float*)(h1 + (size_t)N_NODES * D1);  // N*64
    float* yr    = yl + (size_t)N_NODES * NCLS;          // N*64
    int* cnt     = (int*)(yr + (size_t)N_NODES * NCLS);  // N
    int* pscan   = cnt + N_NODES;                        // N
    int* bsum    = pscan + N_NODES;                      // 128
    int* row_ptr = bsum + 128;                           // N+1
    int* cursor  = row_ptr + N_NODES + 1;                // N
    int* csr_src = cursor + N_NODES;                     // E

    // conversions (bf16 inputs for MFMA GEMMs)
    convert_bf16_vec<<<(N_NODES * F_IN / 4 + 255) / 256, 256, 0, stream>>>(x, xbf, N_NODES * F_IN / 4);
    transpose_w_bf16<<<(D1 * F_IN + 255) / 256, 256, 0, stream>>>(Wl1, wt1l, 8, D1, D1 * F_IN);
    transpose_w_bf16<<<(D1 * F_IN + 255) / 256, 256, 0, stream>>>(Wr1, wt1r, 8, D1, D1 * F_IN);
    transpose_w_bf16<<<(NCLS * D1 + 255) / 256, 256, 0, stream>>>(Wl2, wt2l, 9, NCLS, NCLS * D1);
    transpose_w_bf16<<<(NCLS * D1 + 255) / 256, 256, 0, stream>>>(Wr2, wt2r, 9, NCLS, NCLS * D1);

    // CSR build
    hipMemsetAsync(cnt, 0, N_NODES * sizeof(int), stream);
    hist_kernel<<<N_EDGES / 256, 256, 0, stream>>>(dstv, cnt, N_EDGES);
    scan_local<<<SCAN_BLOCKS, 256, 0, stream>>>(cnt, pscan, bsum, N_NODES);
    scan_block<<<1, 128, 0, stream>>>(bsum, SCAN_BLOCKS);
    scan_finalize<<<SCAN_BLOCKS, 256, 0, stream>>>(cnt, pscan, bsum, row_ptr, cursor, N_NODES);
    scatter_kernel<<<N_EDGES / 256, 256, 0, stream>>>(srcv, dstv, cursor, csr_src, N_EDGES);

    // layer 1 projections (bf16 MFMA)
    gemm_mfma_bt<<<dim3(D1 / 64, (N_NODES + 127) / 128), 256, 0, stream>>>(xbf, wt1l, xl1, N_NODES, D1, F_IN);
    gemm_mfma_bt<<<dim3(D1 / 64, (N_NODES + 127) / 128), 256, 0, stream>>>(xbf, wt1r, xr1, N_NODES, D1, F_IN);
    // layer 1 fused attention + bias + ELU -> bf16 h1
    attn_l1_fused<<<N_NODES, 256, 0, stream>>>(xl1, xr1, att1, b1, row_ptr, csr_src, h1);
    // layer 2 projections (bf16 MFMA)
    gemm_mfma_bt<<<dim3(NCLS / 64, (N_NODES + 127) / 128), 256, 0, stream>>>(h1, wt2l, yl, N_NODES, NCLS, D1);
    gemm_mfma_bt<<<dim3(NCLS / 64, (N_NODES + 127) / 128), 256, 0, stream>>>(h1, wt2r, yr, N_NODES, NCLS, D1);
    // layer 2 fused attention + bias
    attn_l2_fused<<<(N_NODES + 3) / 4, 256, 0, stream>>>(yl, yr, att2, b2, row_ptr, csr_src, out);
}

// Round 5
// 263.760 us; speedup vs baseline: 2.4187x; 1.2453x over previous
//
#include <hip/hip_runtime.h>
#include <hip/hip_bf16.h>

#define N_NODES 20000
#define N_EDGES 320000
#define F_IN 256
#define HID 64
#define HEADS 8
#define NCLS 64
#define D1 (HEADS * HID)   // 512
#define NEG_SLOPE 0.2f
#define SCAN_BLOCKS ((N_NODES + 255) / 256)   // 79

typedef __attribute__((ext_vector_type(8))) short short8;
typedef __attribute__((ext_vector_type(4))) float floatx4;

__device__ __forceinline__ ushort f2bf(float f) {
    unsigned u = __float_as_uint(f);
    unsigned r = (u + 0x7fffu + ((u >> 16) & 1u)) >> 16;
    return (ushort)r;
}
__device__ __forceinline__ float bf2f(ushort u) {
    return __uint_as_float((unsigned)u << 16);
}

// ---------- conversions ----------
__global__ __launch_bounds__(256) void convert_bf16_vec(const float* __restrict__ in,
                                                        ushort* __restrict__ out, int n4) {
    int i = blockIdx.x * 256 + threadIdx.x;
    if (i < n4) {
        float4 v = ((const float4*)in)[i];
        ushort4 o;
        o.x = f2bf(v.x); o.y = f2bf(v.y); o.z = f2bf(v.z); o.w = f2bf(v.w);
        ((ushort4*)out)[i] = o;
    }
}

// W [Kd][Nd] fp32 -> Wt [Nd][Kd] bf16 (Kd = 1<<kshift)
__global__ __launch_bounds__(256) void transpose_w_bf16(const float* __restrict__ W,
                                                        ushort* __restrict__ Wt,
                                                        int kshift, int Nd, int total) {
    int i = blockIdx.x * 256 + threadIdx.x;
    if (i < total) {
        int n = i >> kshift, k = i & ((1 << kshift) - 1);
        Wt[i] = f2bf(W[(size_t)k * Nd + n]);
    }
}

// ---------- CSR build ----------
__global__ void hist_kernel(const int* __restrict__ dst, int* __restrict__ cnt, int E) {
    int i = blockIdx.x * 256 + threadIdx.x;
    if (i < E) atomicAdd(&cnt[dst[i]], 1);
}

__global__ __launch_bounds__(256) void scan_local(const int* __restrict__ cnt,
                                                  int* __restrict__ pscan,
                                                  int* __restrict__ bsum, int n) {
    int tid = threadIdx.x;
    int i = blockIdx.x * 256 + tid;
    int lane = tid & 63, wave = tid >> 6;
    int v = (i < n) ? cnt[i] : 0;
    int x = v;
    #pragma unroll
    for (int d = 1; d < 64; d <<= 1) {
        int y = __shfl_up(x, d);
        if (lane >= d) x += y;
    }
    __shared__ int wsum[4];
    if (lane == 63) wsum[wave] = x;
    __syncthreads();
    int woff = 0;
    for (int w2 = 0; w2 < wave; w2++) woff += wsum[w2];
    int incl = x + woff;
    if (i < n) pscan[i] = incl;
    if (tid == 255) bsum[blockIdx.x] = incl;
}

__global__ __launch_bounds__(128) void scan_block(int* __restrict__ bsum, int nb) {
    int tid = threadIdx.x;
    __shared__ int sh[128];
    int v = (tid < nb) ? bsum[tid] : 0;
    sh[tid] = v;
    __syncthreads();
    #pragma unroll
    for (int d = 1; d < 128; d <<= 1) {
        int x = (tid >= d) ? sh[tid - d] : 0;
        __syncthreads();
        sh[tid] += x;
        __syncthreads();
    }
    if (tid < nb) bsum[tid] = sh[tid] - v;   // exclusive block offsets
}

__global__ __launch_bounds__(256) void scan_finalize(const int* __restrict__ cnt,
                                                     const int* __restrict__ pscan,
                                                     const int* __restrict__ bsum,
                                                     int* __restrict__ row_ptr,
                                                     int* __restrict__ cursor, int n) {
    int i = blockIdx.x * 256 + threadIdx.x;
    if (i < n) {
        int incl = pscan[i] + bsum[blockIdx.x];
        row_ptr[i + 1] = incl;
        cursor[i] = incl - cnt[i];
    }
    if (i == 0) row_ptr[0] = 0;
}

__global__ void scatter_kernel(const int* __restrict__ src, const int* __restrict__ dst,
                               int* __restrict__ cursor, int* __restrict__ csr_src, int E) {
    int i = blockIdx.x * 256 + threadIdx.x;
    if (i < E) {
        int d = dst[i];
        int pos = atomicAdd(&cursor[d], 1);
        csr_src[pos] = src[i];
    }
}

// ---------- bf16 MFMA GEMM, bf16 output: C[M,N] = A[M,K] @ Bt[N,K]^T ----------
// tile 128M x 64N, 256 threads (4 waves); wave w owns rows w*32..w*32+31.
#define APAD 40
__global__ __launch_bounds__(256) void gemm_mfma_bt_bf16(
    const ushort* __restrict__ A, const ushort* __restrict__ Bt,
    ushort* __restrict__ C, int M, int N, int K) {
    __shared__ ushort As[128 * APAD];
    __shared__ ushort Bs[64 * APAD];
    int tid = threadIdx.x;
    int rowBase = blockIdx.y * 128, colBase = blockIdx.x * 64;
    int wave = tid >> 6, lane = tid & 63;
    int quad = lane >> 4, m16 = lane & 15;
    floatx4 acc[2][4];
    #pragma unroll
    for (int i = 0; i < 2; i++)
        #pragma unroll
        for (int j = 0; j < 4; j++) acc[i][j] = (floatx4){0.f, 0.f, 0.f, 0.f};

    for (int k0 = 0; k0 < K; k0 += 32) {
        #pragma unroll
        for (int i = 0; i < 2; i++) {
            int idx = i * 256 + tid;
            int r = idx >> 2, kq = (idx & 3) * 8;
            int grow = rowBase + r;
            uint4 v = make_uint4(0, 0, 0, 0);
            if (grow < M) v = *(const uint4*)(A + (size_t)grow * K + k0 + kq);
            *(uint4*)&As[r * APAD + kq] = v;
        }
        {
            int r = tid >> 2, kq = (tid & 3) * 8;
            uint4 v = *(const uint4*)(Bt + (size_t)(colBase + r) * K + k0 + kq);
            *(uint4*)&Bs[r * APAD + kq] = v;
        }
        __syncthreads();
        short8 a0 = *(short8*)&As[(wave * 32 + m16) * APAD + quad * 8];
        short8 a1 = *(short8*)&As[(wave * 32 + 16 + m16) * APAD + quad * 8];
        #pragma unroll
        for (int ct = 0; ct < 4; ct++) {
            short8 b = *(short8*)&Bs[(ct * 16 + m16) * APAD + quad * 8];
            acc[0][ct] = __builtin_amdgcn_mfma_f32_16x16x32_bf16(a0, b, acc[0][ct], 0, 0, 0);
            acc[1][ct] = __builtin_amdgcn_mfma_f32_16x16x32_bf16(a1, b, acc[1][ct], 0, 0, 0);
        }
        __syncthreads();
    }
    // epilogue: C/D layout col=lane&15, row=quad*4+reg; store bf16
    #pragma unroll
    for (int rt = 0; rt < 2; rt++)
        #pragma unroll
        for (int ct = 0; ct < 4; ct++)
            #pragma unroll
            for (int r = 0; r < 4; r++) {
                int row = rowBase + wave * 32 + rt * 16 + quad * 4 + r;
                if (row < M) C[(size_t)row * N + colBase + ct * 16 + m16] = f2bf(acc[rt][ct][r]);
            }
}

// ---------- layer-1 fused attention: bf16 gather, 4 ch/thread, 128 thr/block ----------
// thread t owns channels 4t..4t+3 (head = t>>4); 16-lane head groups -> 4-step butterfly.
// xlr row layout: [0..511]=xl, [512..1023]=xr (bf16).
__global__ __launch_bounds__(128) void attn_l1_fused(
    const ushort* __restrict__ xlr, const float* __restrict__ att,
    const float* __restrict__ b1,
    const int* __restrict__ row_ptr, const int* __restrict__ csr_src,
    ushort* __restrict__ h1out) {
    int d = blockIdx.x, t = threadIdx.x;
    int start = row_ptr[d], deg = row_ptr[d + 1] - start;

    ushort4 xru = *(const ushort4*)(xlr + (size_t)d * 1024 + 512 + 4 * t);
    float xr0 = bf2f(xru.x), xr1 = bf2f(xru.y), xr2 = bf2f(xru.z), xr3 = bf2f(xru.w);
    float4 atv = *(const float4*)(att + 4 * t);

    float den = 0.f, acc0 = 0.f, acc1 = 0.f, acc2 = 0.f, acc3 = 0.f;

    if (deg > 0) {
        ushort4 xv[4];
        #pragma unroll
        for (int j = 0; j < 4; j++) {
            int p = min(j, deg - 1);
            int s = csr_src[start + p];
            xv[j] = *(const ushort4*)(xlr + (size_t)s * 1024 + 4 * t);
        }
        for (int p0 = 0; p0 < deg; p0 += 4) {
            ushort4 u0 = xv[0], u1 = xv[1], u2 = xv[2], u3 = xv[3];
            #pragma unroll
            for (int j = 0; j < 4; j++) {
                int p = p0 + 4 + j;
                if (p < deg) {
                    int s = csr_src[start + p];
                    xv[j] = *(const ushort4*)(xlr + (size_t)s * 1024 + 4 * t);
                }
            }
            float c00 = bf2f(u0.x), c01 = bf2f(u0.y), c02 = bf2f(u0.z), c03 = bf2f(u0.w);
            float c10 = bf2f(u1.x), c11 = bf2f(u1.y), c12 = bf2f(u1.z), c13 = bf2f(u1.w);
            float c20 = bf2f(u2.x), c21 = bf2f(u2.y), c22 = bf2f(u2.z), c23 = bf2f(u2.w);
            float c30 = bf2f(u3.x), c31 = bf2f(u3.y), c32 = bf2f(u3.z), c33 = bf2f(u3.w);
            float v;
            float p0v, p1v, p2v, p3v;
            v = c00 + xr0; v = v > 0.f ? v : NEG_SLOPE * v; p0v = atv.x * v;
            v = c01 + xr1; v = v > 0.f ? v : NEG_SLOPE * v; p0v = fmaf(atv.y, v, p0v);
            v = c02 + xr2; v = v > 0.f ? v : NEG_SLOPE * v; p0v = fmaf(atv.z, v, p0v);
            v = c03 + xr3; v = v > 0.f ? v : NEG_SLOPE * v; p0v = fmaf(atv.w, v, p0v);
            v = c10 + xr0; v = v > 0.f ? v : NEG_SLOPE * v; p1v = atv.x * v;
            v = c11 + xr1; v = v > 0.f ? v : NEG_SLOPE * v; p1v = fmaf(atv.y, v, p1v);
            v = c12 + xr2; v = v > 0.f ? v : NEG_SLOPE * v; p1v = fmaf(atv.z, v, p1v);
            v = c13 + xr3; v = v > 0.f ? v : NEG_SLOPE * v; p1v = fmaf(atv.w, v, p1v);
            v = c20 + xr0; v = v > 0.f ? v : NEG_SLOPE * v; p2v = atv.x * v;
            v = c21 + xr1; v = v > 0.f ? v : NEG_SLOPE * v; p2v = fmaf(atv.y, v, p2v);
            v = c22 + xr2; v = v > 0.f ? v : NEG_SLOPE * v; p2v = fmaf(atv.z, v, p2v);
            v = c23 + xr3; v = v > 0.f ? v : NEG_SLOPE * v; p2v = fmaf(atv.w, v, p2v);
            v = c30 + xr0; v = v > 0.f ? v : NEG_SLOPE * v; p3v = atv.x * v;
            v = c31 + xr1; v = v > 0.f ? v : NEG_SLOPE * v; p3v = fmaf(atv.y, v, p3v);
            v = c32 + xr2; v = v > 0.f ? v : NEG_SLOPE * v; p3v = fmaf(atv.z, v, p3v);
            v = c33 + xr3; v = v > 0.f ? v : NEG_SLOPE * v; p3v = fmaf(atv.w, v, p3v);
            #pragma unroll
            for (int mask = 1; mask < 16; mask <<= 1) {
                p0v += __shfl_xor(p0v, mask);
                p1v += __shfl_xor(p1v, mask);
                p2v += __shfl_xor(p2v, mask);
                p3v += __shfl_xor(p3v, mask);
            }
            float e0 = (p0 + 0 < deg) ? __expf(p0v) : 0.f;
            float e1 = (p0 + 1 < deg) ? __expf(p1v) : 0.f;
            float e2 = (p0 + 2 < deg) ? __expf(p2v) : 0.f;
            float e3 = (p0 + 3 < deg) ? __expf(p3v) : 0.f;
            den += (e0 + e1) + (e2 + e3);
            acc0 = fmaf(e0, c00, fmaf(e1, c10, fmaf(e2, c20, fmaf(e3, c30, acc0))));
            acc1 = fmaf(e0, c01, fmaf(e1, c11, fmaf(e2, c21, fmaf(e3, c31, acc1))));
            acc2 = fmaf(e0, c02, fmaf(e1, c12, fmaf(e2, c22, fmaf(e3, c32, acc2))));
            acc3 = fmaf(e0, c03, fmaf(e1, c13, fmaf(e2, c23, fmaf(e3, c33, acc3))));
        }
    }
    float inv = 1.f / (den + 1e-16f);
    float4 bv = *(const float4*)(b1 + 4 * t);
    float o0 = acc0 * inv + bv.x;
    float o1 = acc1 * inv + bv.y;
    float o2 = acc2 * inv + bv.z;
    float o3 = acc3 * inv + bv.w;
    o0 = o0 > 0.f ? o0 : (__expf(o0) - 1.f);   // ELU
    o1 = o1 > 0.f ? o1 : (__expf(o1) - 1.f);
    o2 = o2 > 0.f ? o2 : (__expf(o2) - 1.f);
    o3 = o3 > 0.f ? o3 : (__expf(o3) - 1.f);
    ushort4 hv;
    hv.x = f2bf(o0); hv.y = f2bf(o1); hv.z = f2bf(o2); hv.w = f2bf(o3);
    *(ushort4*)(h1out + (size_t)d * D1 + 4 * t) = hv;
}

// ---------- layer-2 fused attention: bf16 gather; wave/node, 4-deep pipeline ----------
// ylr row layout: [0..63]=yl, [64..127]=yr (bf16).
__global__ __launch_bounds__(256) void attn_l2_fused(
    const ushort* __restrict__ ylr, const float* __restrict__ att2,
    const float* __restrict__ b2,
    const int* __restrict__ row_ptr, const int* __restrict__ csr_src,
    float* __restrict__ out) {
    int wave = threadIdx.x >> 6, lane = threadIdx.x & 63;
    int d = blockIdx.x * 4 + wave;
    if (d >= N_NODES) return;
    int start = row_ptr[d], deg = row_ptr[d + 1] - start;

    float yrv = bf2f(ylr[(size_t)d * 128 + 64 + lane]);
    float attv = att2[lane];
    float den = 0.f, acc = 0.f;

    if (deg > 0) {
        float yv[4];
        #pragma unroll
        for (int j = 0; j < 4; j++) {
            int p = min(j, deg - 1);
            int s = csr_src[start + p];
            yv[j] = bf2f(ylr[(size_t)s * 128 + lane]);
        }
        for (int p0 = 0; p0 < deg; p0 += 4) {
            float c0 = yv[0], c1 = yv[1], c2 = yv[2], c3 = yv[3];
            #pragma unroll
            for (int j = 0; j < 4; j++) {
                int p = p0 + 4 + j;
                if (p < deg) {
                    int s = csr_src[start + p];
                    yv[j] = bf2f(ylr[(size_t)s * 128 + lane]);
                }
            }
            float v;
            v = c0 + yrv; v = v > 0.f ? v : NEG_SLOPE * v; float a0 = attv * v;
            v = c1 + yrv; v = v > 0.f ? v : NEG_SLOPE * v; float a1 = attv * v;
            v = c2 + yrv; v = v > 0.f ? v : NEG_SLOPE * v; float a2 = attv * v;
            v = c3 + yrv; v = v > 0.f ? v : NEG_SLOPE * v; float a3 = attv * v;
            #pragma unroll
            for (int mask = 1; mask < 64; mask <<= 1) {
                a0 += __shfl_xor(a0, mask);
                a1 += __shfl_xor(a1, mask);
                a2 += __shfl_xor(a2, mask);
                a3 += __shfl_xor(a3, mask);
            }
            float e0 = (p0 + 0 < deg) ? __expf(a0) : 0.f;
            float e1 = (p0 + 1 < deg) ? __expf(a1) : 0.f;
            float e2 = (p0 + 2 < deg) ? __expf(a2) : 0.f;
            float e3 = (p0 + 3 < deg) ? __expf(a3) : 0.f;
            den += (e0 + e1) + (e2 + e3);
            acc = fmaf(e0, c0, fmaf(e1, c1, fmaf(e2, c2, fmaf(e3, c3, acc))));
        }
    }
    out[(size_t)d * NCLS + lane] = acc / (den + 1e-16f) + b2[lane];
}

extern "C" void kernel_launch(void* const* d_in, const int* in_sizes, int n_in,
                              void* d_out, int out_size, void* d_ws, size_t ws_size,
                              hipStream_t stream) {
    const float* x    = (const float*)d_in[0];
    const int*   edge = (const int*)d_in[1];
    const float* Wl1  = (const float*)d_in[2];
    const float* Wr1  = (const float*)d_in[3];
    const float* att1 = (const float*)d_in[4];
    const float* b1   = (const float*)d_in[5];
    const float* Wl2  = (const float*)d_in[6];
    const float* Wr2  = (const float*)d_in[7];
    const float* att2 = (const float*)d_in[8];
    const float* b2   = (const float*)d_in[9];
    float* out = (float*)d_out;

    const int* srcv = edge;
    const int* dstv = edge + N_EDGES;

    ushort* xbf  = (ushort*)d_ws;                        // N*256
    ushort* wt1  = xbf + (size_t)N_NODES * F_IN;         // 1024*256 (Wl1^T || Wr1^T)
    ushort* wt2  = wt1 + 2 * D1 * F_IN;                  // 128*512  (Wl2^T || Wr2^T)
    ushort* xlr  = wt2 + 2 * NCLS * D1;                  // N*1024 bf16
    ushort* h1   = xlr + (size_t)N_NODES * 2 * D1;       // N*512 bf16
    ushort* ylr  = h1 + (size_t)N_NODES * D1;            // N*128 bf16
    int* cnt     = (int*)(ylr + (size_t)N_NODES * 2 * NCLS);
    int* pscan   = cnt + N_NODES;                        // N
    int* bsum    = pscan + N_NODES;                      // 128
    int* row_ptr = bsum + 128;                           // N+1
    int* cursor  = row_ptr + N_NODES + 1;                // N
    int* csr_src = cursor + N_NODES;                     // E

    // conversions: bf16 x and concatenated transposed weights
    convert_bf16_vec<<<(N_NODES * F_IN / 4 + 255) / 256, 256, 0, stream>>>(x, xbf, N_NODES * F_IN / 4);
    transpose_w_bf16<<<(D1 * F_IN + 255) / 256, 256, 0, stream>>>(Wl1, wt1, 8, D1, D1 * F_IN);
    transpose_w_bf16<<<(D1 * F_IN + 255) / 256, 256, 0, stream>>>(Wr1, wt1 + D1 * F_IN, 8, D1, D1 * F_IN);
    transpose_w_bf16<<<(NCLS * D1 + 255) / 256, 256, 0, stream>>>(Wl2, wt2, 9, NCLS, NCLS * D1);
    transpose_w_bf16<<<(NCLS * D1 + 255) / 256, 256, 0, stream>>>(Wr2, wt2 + NCLS * D1, 9, NCLS, NCLS * D1);

    // CSR build
    hipMemsetAsync(cnt, 0, N_NODES * sizeof(int), stream);
    hist_kernel<<<N_EDGES / 256, 256, 0, stream>>>(dstv, cnt, N_EDGES);
    scan_local<<<SCAN_BLOCKS, 256, 0, stream>>>(cnt, pscan, bsum, N_NODES);
    scan_block<<<1, 128, 0, stream>>>(bsum, SCAN_BLOCKS);
    scan_finalize<<<SCAN_BLOCKS, 256, 0, stream>>>(cnt, pscan, bsum, row_ptr, cursor, N_NODES);
    scatter_kernel<<<N_EDGES / 256, 256, 0, stream>>>(srcv, dstv, cursor, csr_src, N_EDGES);

    // layer 1 projection (fused l+r): xlr[N][1024] bf16
    gemm_mfma_bt_bf16<<<dim3(2 * D1 / 64, (N_NODES + 127) / 128), 256, 0, stream>>>(
        xbf, wt1, xlr, N_NODES, 2 * D1, F_IN);
    // layer 1 fused attention + bias + ELU -> bf16 h1
    attn_l1_fused<<<N_NODES, 128, 0, stream>>>(xlr, att1, b1, row_ptr, csr_src, h1);
    // layer 2 projection (fused l+r): ylr[N][128] bf16
    gemm_mfma_bt_bf16<<<dim3(2 * NCLS / 64, (N_NODES + 127) / 128), 256, 0, stream>>>(
        h1, wt2, ylr, N_NODES, 2 * NCLS, D1);
    // layer 2 fused attention + bias
    attn_l2_fused<<<(N_NODES + 3) / 4, 256, 0, stream>>>(ylr, att2, b2, row_ptr, csr_src, out);
}

// Round 6
// 238.572 us; speedup vs baseline: 2.6741x; 1.1056x over previous
//
#include <hip/hip_runtime.h>
#include <hip/hip_bf16.h>

#define N_NODES 20000
#define N_EDGES 320000
#define F_IN 256
#define HID 64
#define HEADS 8
#define NCLS 64
#define D1 (HEADS * HID)   // 512
#define SCAN_BLOCKS ((N_NODES + 255) / 256)   // 79

typedef __attribute__((ext_vector_type(8))) short short8;
typedef __attribute__((ext_vector_type(4))) float floatx4;
typedef __attribute__((ext_vector_type(2))) float v2f;

__device__ __forceinline__ ushort f2bf(float f) {
    unsigned u = __float_as_uint(f);
    unsigned r = (u + 0x7fffu + ((u >> 16) & 1u)) >> 16;
    return (ushort)r;
}
__device__ __forceinline__ float bf2f(ushort u) {
    return __uint_as_float((unsigned)u << 16);
}
// unpack 2 packed bf16 (one u32) -> float2; low ushort = first channel
__device__ __forceinline__ v2f unpack2(unsigned u) {
    v2f r;
    r.x = __uint_as_float(u << 16);
    r.y = __uint_as_float(u & 0xffff0000u);
    return r;
}
// DPP-fused add: x + dpp(x); pure VALU, no LDS pipe
template <int CTRL>
__device__ __forceinline__ float dppadd(float x) {
    int y = __builtin_amdgcn_update_dpp(0, __float_as_int(x), CTRL, 0xF, 0xF, true);
    return x + __int_as_float(y);
}
// sum over 16-lane row: quad xor1, xor2, row_ror:4, row_ror:8
__device__ __forceinline__ float rowsum16(float x) {
    x = dppadd<0xB1>(x);    // quad_perm [1,0,3,2]
    x = dppadd<0x4E>(x);    // quad_perm [2,3,0,1]
    x = dppadd<0x124>(x);   // row_ror:4
    x = dppadd<0x128>(x);   // row_ror:8
    return x;
}
// extend to 32 lanes with one ds_swizzle xor16
__device__ __forceinline__ float rowsum32(float x) {
    x = rowsum16(x);
    float t = __int_as_float(__builtin_amdgcn_ds_swizzle(__float_as_int(x), 0x401F));
    return x + t;
}

// ---------- fused preprocess: x->bf16, 4 weight transposes, dst histogram ----------
#define PB_HIST 1250
#define PB_CONV 5000
#define PB_T1   512
#define PB_T2   128
#define PB_TOTAL (PB_HIST + PB_CONV + 2 * PB_T1 + 2 * PB_T2)  // 7530
__global__ __launch_bounds__(256) void preprocess(
    const float* __restrict__ x, ushort* __restrict__ xbf,
    const float* __restrict__ Wl1, const float* __restrict__ Wr1,
    const float* __restrict__ Wl2, const float* __restrict__ Wr2,
    ushort* __restrict__ wt1, ushort* __restrict__ wt2,
    const int* __restrict__ dst, int* __restrict__ cnt) {
    int b = blockIdx.x, t = threadIdx.x;
    if (b < PB_HIST) {
        int i = b * 256 + t;
        if (i < N_EDGES) atomicAdd(&cnt[dst[i]], 1);
    } else if (b < PB_HIST + PB_CONV) {
        int i = (b - PB_HIST) * 256 + t;   // float4 index
        if (i < N_NODES * F_IN / 4) {
            float4 v = ((const float4*)x)[i];
            ushort4 o;
            o.x = f2bf(v.x); o.y = f2bf(v.y); o.z = f2bf(v.z); o.w = f2bf(v.w);
            ((ushort4*)xbf)[i] = o;
        }
    } else if (b < PB_HIST + PB_CONV + 2 * PB_T1) {
        int lb = b - PB_HIST - PB_CONV;
        const float* W = (lb < PB_T1) ? Wl1 : Wr1;
        ushort* Wt = wt1 + ((lb < PB_T1) ? 0 : D1 * F_IN);
        int i = (lb % PB_T1) * 256 + t;    // i = n*256 + k, Kd=256
        if (i < D1 * F_IN) {
            int n = i >> 8, k = i & 255;
            Wt[i] = f2bf(W[(size_t)k * D1 + n]);
        }
    } else {
        int lb = b - PB_HIST - PB_CONV - 2 * PB_T1;
        const float* W = (lb < PB_T2) ? Wl2 : Wr2;
        ushort* Wt = wt2 + ((lb < PB_T2) ? 0 : NCLS * D1);
        int i = (lb % PB_T2) * 256 + t;    // Kd=512
        if (i < NCLS * D1) {
            int n = i >> 9, k = i & 511;
            Wt[i] = f2bf(W[(size_t)k * NCLS + n]);
        }
    }
}

// ---------- CSR scan + scatter ----------
__global__ __launch_bounds__(256) void scan_local(const int* __restrict__ cnt,
                                                  int* __restrict__ pscan,
                                                  int* __restrict__ bsum, int n) {
    int tid = threadIdx.x;
    int i = blockIdx.x * 256 + tid;
    int lane = tid & 63, wave = tid >> 6;
    int v = (i < n) ? cnt[i] : 0;
    int x = v;
    #pragma unroll
    for (int d = 1; d < 64; d <<= 1) {
        int y = __shfl_up(x, d);
        if (lane >= d) x += y;
    }
    __shared__ int wsum[4];
    if (lane == 63) wsum[wave] = x;
    __syncthreads();
    int woff = 0;
    for (int w2 = 0; w2 < wave; w2++) woff += wsum[w2];
    int incl = x + woff;
    if (i < n) pscan[i] = incl;
    if (tid == 255) bsum[blockIdx.x] = incl;
}

__global__ __launch_bounds__(128) void scan_block(int* __restrict__ bsum, int nb) {
    int tid = threadIdx.x;
    __shared__ int sh[128];
    int v = (tid < nb) ? bsum[tid] : 0;
    sh[tid] = v;
    __syncthreads();
    #pragma unroll
    for (int d = 1; d < 128; d <<= 1) {
        int x = (tid >= d) ? sh[tid - d] : 0;
        __syncthreads();
        sh[tid] += x;
        __syncthreads();
    }
    if (tid < nb) bsum[tid] = sh[tid] - v;
}

__global__ __launch_bounds__(256) void scan_finalize(const int* __restrict__ cnt,
                                                     const int* __restrict__ pscan,
                                                     const int* __restrict__ bsum,
                                                     int* __restrict__ row_ptr,
                                                     int* __restrict__ cursor, int n) {
    int i = blockIdx.x * 256 + threadIdx.x;
    if (i < n) {
        int incl = pscan[i] + bsum[blockIdx.x];
        row_ptr[i + 1] = incl;
        cursor[i] = incl - cnt[i];
    }
    if (i == 0) row_ptr[0] = 0;
}

__global__ void scatter_kernel(const int* __restrict__ src, const int* __restrict__ dst,
                               int* __restrict__ cursor, int* __restrict__ csr_src, int E) {
    int i = blockIdx.x * 256 + threadIdx.x;
    if (i < E) {
        int d = dst[i];
        int pos = atomicAdd(&cursor[d], 1);
        csr_src[pos] = src[i];
    }
}

// ---------- bf16 MFMA GEMM, bf16 output: C[M,N] = A[M,K] @ Bt[N,K]^T ----------
#define APAD 40
__global__ __launch_bounds__(256) void gemm_mfma_bt_bf16(
    const ushort* __restrict__ A, const ushort* __restrict__ Bt,
    ushort* __restrict__ C, int M, int N, int K) {
    __shared__ ushort As[128 * APAD];
    __shared__ ushort Bs[64 * APAD];
    int tid = threadIdx.x;
    int rowBase = blockIdx.y * 128, colBase = blockIdx.x * 64;
    int wave = tid >> 6, lane = tid & 63;
    int quad = lane >> 4, m16 = lane & 15;
    floatx4 acc[2][4];
    #pragma unroll
    for (int i = 0; i < 2; i++)
        #pragma unroll
        for (int j = 0; j < 4; j++) acc[i][j] = (floatx4){0.f, 0.f, 0.f, 0.f};

    for (int k0 = 0; k0 < K; k0 += 32) {
        #pragma unroll
        for (int i = 0; i < 2; i++) {
            int idx = i * 256 + tid;
            int r = idx >> 2, kq = (idx & 3) * 8;
            int grow = rowBase + r;
            uint4 v = make_uint4(0, 0, 0, 0);
            if (grow < M) v = *(const uint4*)(A + (size_t)grow * K + k0 + kq);
            *(uint4*)&As[r * APAD + kq] = v;
        }
        {
            int r = tid >> 2, kq = (tid & 3) * 8;
            uint4 v = *(const uint4*)(Bt + (size_t)(colBase + r) * K + k0 + kq);
            *(uint4*)&Bs[r * APAD + kq] = v;
        }
        __syncthreads();
        short8 a0 = *(short8*)&As[(wave * 32 + m16) * APAD + quad * 8];
        short8 a1 = *(short8*)&As[(wave * 32 + 16 + m16) * APAD + quad * 8];
        #pragma unroll
        for (int ct = 0; ct < 4; ct++) {
            short8 b = *(short8*)&Bs[(ct * 16 + m16) * APAD + quad * 8];
            acc[0][ct] = __builtin_amdgcn_mfma_f32_16x16x32_bf16(a0, b, acc[0][ct], 0, 0, 0);
            acc[1][ct] = __builtin_amdgcn_mfma_f32_16x16x32_bf16(a1, b, acc[1][ct], 0, 0, 0);
        }
        __syncthreads();
    }
    #pragma unroll
    for (int rt = 0; rt < 2; rt++)
        #pragma unroll
        for (int ct = 0; ct < 4; ct++)
            #pragma unroll
            for (int r = 0; r < 4; r++) {
                int row = rowBase + wave * 32 + rt * 16 + quad * 4 + r;
                if (row < M) C[(size_t)row * N + colBase + ct * 16 + m16] = f2bf(acc[rt][ct][r]);
            }
}

// ---------- layer-1 fused attention ----------
// 128 thr/block, thread t owns channels 4t..4t+3 (16-lane head groups).
// Score: a*leaky(v) = 0.6a*v + 0.4a*|v|; DPP-only 16-lane reduction; packed f32 math.
__global__ __launch_bounds__(128) void attn_l1_fused(
    const ushort* __restrict__ xlr, const float* __restrict__ att,
    const float* __restrict__ b1,
    const int* __restrict__ row_ptr, const int* __restrict__ csr_src,
    ushort* __restrict__ h1out) {
    int d = blockIdx.x, t = threadIdx.x;
    int start = row_ptr[d], deg = row_ptr[d + 1] - start;

    uint2 xru = *(const uint2*)(xlr + (size_t)d * 1024 + 512 + 4 * t);
    v2f xr01 = unpack2(xru.x), xr23 = unpack2(xru.y);
    float4 atv = *(const float4*)(att + 4 * t);
    v2f at6_01 = {0.6f * atv.x, 0.6f * atv.y}, at6_23 = {0.6f * atv.z, 0.6f * atv.w};
    v2f at4_01 = {0.4f * atv.x, 0.4f * atv.y}, at4_23 = {0.4f * atv.z, 0.4f * atv.w};

    float den = 0.f;
    v2f acc01 = {0.f, 0.f}, acc23 = {0.f, 0.f};

    if (deg > 0) {
        uint2 xv[4];
        #pragma unroll
        for (int j = 0; j < 4; j++) {
            int s = csr_src[start + min(j, deg - 1)];
            xv[j] = *(const uint2*)(xlr + (size_t)s * 1024 + 4 * t);
        }
        for (int p0 = 0; p0 < deg; p0 += 4) {
            uint2 u0 = xv[0], u1 = xv[1], u2 = xv[2], u3 = xv[3];
            #pragma unroll
            for (int j = 0; j < 4; j++) {
                int p = p0 + 4 + j;
                if (p < deg) {
                    int s = csr_src[start + p];
                    xv[j] = *(const uint2*)(xlr + (size_t)s * 1024 + 4 * t);
                }
            }
            v2f c01_0 = unpack2(u0.x), c23_0 = unpack2(u0.y);
            v2f c01_1 = unpack2(u1.x), c23_1 = unpack2(u1.y);
            v2f c01_2 = unpack2(u2.x), c23_2 = unpack2(u2.y);
            v2f c01_3 = unpack2(u3.x), c23_3 = unpack2(u3.y);

            v2f va, vb, sp;
            va = c01_0 + xr01; vb = c23_0 + xr23;
            sp = at6_01 * va + at4_01 * __builtin_elementwise_abs(va)
               + at6_23 * vb + at4_23 * __builtin_elementwise_abs(vb);
            float s0 = sp.x + sp.y;
            va = c01_1 + xr01; vb = c23_1 + xr23;
            sp = at6_01 * va + at4_01 * __builtin_elementwise_abs(va)
               + at6_23 * vb + at4_23 * __builtin_elementwise_abs(vb);
            float s1 = sp.x + sp.y;
            va = c01_2 + xr01; vb = c23_2 + xr23;
            sp = at6_01 * va + at4_01 * __builtin_elementwise_abs(va)
               + at6_23 * vb + at4_23 * __builtin_elementwise_abs(vb);
            float s2 = sp.x + sp.y;
            va = c01_3 + xr01; vb = c23_3 + xr23;
            sp = at6_01 * va + at4_01 * __builtin_elementwise_abs(va)
               + at6_23 * vb + at4_23 * __builtin_elementwise_abs(vb);
            float s3 = sp.x + sp.y;

            s0 = rowsum16(s0); s1 = rowsum16(s1);
            s2 = rowsum16(s2); s3 = rowsum16(s3);

            float e0 = (p0 + 0 < deg) ? __expf(s0) : 0.f;
            float e1 = (p0 + 1 < deg) ? __expf(s1) : 0.f;
            float e2 = (p0 + 2 < deg) ? __expf(s2) : 0.f;
            float e3 = (p0 + 3 < deg) ? __expf(s3) : 0.f;
            den += (e0 + e1) + (e2 + e3);
            v2f e0v = {e0, e0}, e1v = {e1, e1}, e2v = {e2, e2}, e3v = {e3, e3};
            acc01 = acc01 + e0v * c01_0 + e1v * c01_1 + e2v * c01_2 + e3v * c01_3;
            acc23 = acc23 + e0v * c23_0 + e1v * c23_1 + e2v * c23_2 + e3v * c23_3;
        }
    }
    float inv = 1.f / (den + 1e-16f);
    float4 bv = *(const float4*)(b1 + 4 * t);
    float o0 = acc01.x * inv + bv.x;
    float o1 = acc01.y * inv + bv.y;
    float o2 = acc23.x * inv + bv.z;
    float o3 = acc23.y * inv + bv.w;
    o0 = o0 > 0.f ? o0 : (__expf(o0) - 1.f);   // ELU
    o1 = o1 > 0.f ? o1 : (__expf(o1) - 1.f);
    o2 = o2 > 0.f ? o2 : (__expf(o2) - 1.f);
    o3 = o3 > 0.f ? o3 : (__expf(o3) - 1.f);
    ushort4 hv;
    hv.x = f2bf(o0); hv.y = f2bf(o1); hv.z = f2bf(o2); hv.w = f2bf(o3);
    *(ushort4*)(h1out + (size_t)d * D1 + 4 * t) = hv;
}

// ---------- layer-2 fused attention: half-wave per edge, 2 ch/lane ----------
// ylr row: [0..63]=yl, [64..127]=yr (bf16). Wave w handles node blockIdx*4+w;
// lanes 0..31 process edge 2i, lanes 32..63 edge 2i+1; cross-half combine at end.
__global__ __launch_bounds__(256) void attn_l2_fused(
    const ushort* __restrict__ ylr, const float* __restrict__ att2,
    const float* __restrict__ b2,
    const int* __restrict__ row_ptr, const int* __restrict__ csr_src,
    float* __restrict__ out) {
    int wave = threadIdx.x >> 6, lane = threadIdx.x & 63;
    int d = blockIdx.x * 4 + wave;
    if (d >= N_NODES) return;
    int half = lane >> 5, l31 = lane & 31;
    int start = row_ptr[d], deg = row_ptr[d + 1] - start;

    unsigned yru = *(const unsigned*)(ylr + (size_t)d * 128 + 64 + 2 * l31);
    v2f yr2 = unpack2(yru);
    float2 a2 = *(const float2*)(att2 + 2 * l31);
    v2f at6 = {0.6f * a2.x, 0.6f * a2.y};
    v2f at4 = {0.4f * a2.x, 0.4f * a2.y};

    float den = 0.f;
    v2f acc = {0.f, 0.f};

    if (deg > 0) {
        int S = (deg + 1) >> 1;                 // steps of 2 edges
        unsigned yv[4];
        #pragma unroll
        for (int j = 0; j < 4; j++) {
            int p = min(2 * j + half, deg - 1);
            int s = csr_src[start + p];
            yv[j] = *(const unsigned*)(ylr + (size_t)s * 128 + 2 * l31);
        }
        for (int i = 0; i < S; i++) {
            unsigned cu = yv[i & 3];
            int pf = i + 4;
            if (pf < S) {
                int p = min(2 * pf + half, deg - 1);
                int s = csr_src[start + p];
                yv[i & 3] = *(const unsigned*)(ylr + (size_t)s * 128 + 2 * l31);
            }
            v2f c2 = unpack2(cu);
            v2f v = c2 + yr2;
            v2f sp = at6 * v + at4 * __builtin_elementwise_abs(v);
            float sc = sp.x + sp.y;
            sc = rowsum32(sc);
            float e = (2 * i + half < deg) ? __expf(sc) : 0.f;
            den += e;
            v2f ev = {e, e};
            acc = acc + ev * c2;
        }
        // combine the two halves
        den += __shfl_xor(den, 32);
        acc.x += __shfl_xor(acc.x, 32);
        acc.y += __shfl_xor(acc.y, 32);
    }
    if (half == 0) {
        float inv = 1.f / (den + 1e-16f);
        float2 bv = *(const float2*)(b2 + 2 * l31);
        float2 o;
        o.x = acc.x * inv + bv.x;
        o.y = acc.y * inv + bv.y;
        *(float2*)(out + (size_t)d * NCLS + 2 * l31) = o;
    }
}

extern "C" void kernel_launch(void* const* d_in, const int* in_sizes, int n_in,
                              void* d_out, int out_size, void* d_ws, size_t ws_size,
                              hipStream_t stream) {
    const float* x    = (const float*)d_in[0];
    const int*   edge = (const int*)d_in[1];
    const float* Wl1  = (const float*)d_in[2];
    const float* Wr1  = (const float*)d_in[3];
    const float* att1 = (const float*)d_in[4];
    const float* b1   = (const float*)d_in[5];
    const float* Wl2  = (const float*)d_in[6];
    const float* Wr2  = (const float*)d_in[7];
    const float* att2 = (const float*)d_in[8];
    const float* b2   = (const float*)d_in[9];
    float* out = (float*)d_out;

    const int* srcv = edge;
    const int* dstv = edge + N_EDGES;

    ushort* xbf  = (ushort*)d_ws;                        // N*256
    ushort* wt1  = xbf + (size_t)N_NODES * F_IN;         // 1024*256 (Wl1^T || Wr1^T)
    ushort* wt2  = wt1 + 2 * D1 * F_IN;                  // 128*512  (Wl2^T || Wr2^T)
    ushort* xlr  = wt2 + 2 * NCLS * D1;                  // N*1024 bf16
    ushort* h1   = xlr + (size_t)N_NODES * 2 * D1;       // N*512 bf16
    ushort* ylr  = h1 + (size_t)N_NODES * D1;            // N*128 bf16
    int* cnt     = (int*)(ylr + (size_t)N_NODES * 2 * NCLS);
    int* pscan   = cnt + N_NODES;                        // N
    int* bsum    = pscan + N_NODES;                      // 128
    int* row_ptr = bsum + 128;                           // N+1
    int* cursor  = row_ptr + N_NODES + 1;                // N
    int* csr_src = cursor + N_NODES;                     // E

    hipMemsetAsync(cnt, 0, N_NODES * sizeof(int), stream);
    preprocess<<<PB_TOTAL, 256, 0, stream>>>(x, xbf, Wl1, Wr1, Wl2, Wr2, wt1, wt2, dstv, cnt);
    scan_local<<<SCAN_BLOCKS, 256, 0, stream>>>(cnt, pscan, bsum, N_NODES);
    scan_block<<<1, 128, 0, stream>>>(bsum, SCAN_BLOCKS);
    scan_finalize<<<SCAN_BLOCKS, 256, 0, stream>>>(cnt, pscan, bsum, row_ptr, cursor, N_NODES);
    scatter_kernel<<<N_EDGES / 256, 256, 0, stream>>>(srcv, dstv, cursor, csr_src, N_EDGES);

    // layer 1 projection (fused l+r): xlr[N][1024] bf16
    gemm_mfma_bt_bf16<<<dim3(2 * D1 / 64, (N_NODES + 127) / 128), 256, 0, stream>>>(
        xbf, wt1, xlr, N_NODES, 2 * D1, F_IN);
    attn_l1_fused<<<N_NODES, 128, 0, stream>>>(xlr, att1, b1, row_ptr, csr_src, h1);
    // layer 2 projection (fused l+r): ylr[N][128] bf16
    gemm_mfma_bt_bf16<<<dim3(2 * NCLS / 64, (N_NODES + 127) / 128), 256, 0, stream>>>(
        h1, wt2, ylr, N_NODES, 2 * NCLS, D1);
    attn_l2_fused<<<(N_NODES + 3) / 4, 256, 0, stream>>>(ylr, att2, b2, row_ptr, csr_src, out);
}

// Round 7
// 236.538 us; speedup vs baseline: 2.6970x; 1.0086x over previous
//
#include <hip/hip_runtime.h>
#include <hip/hip_bf16.h>

#define N_NODES 20000
#define N_EDGES 320000
#define F_IN 256
#define HID 64
#define HEADS 8
#define NCLS 64
#define D1 (HEADS * HID)   // 512
#define SCAN_BLOCKS ((N_NODES + 255) / 256)   // 79

typedef __attribute__((ext_vector_type(8))) short short8;
typedef __attribute__((ext_vector_type(4))) float floatx4;
typedef __attribute__((ext_vector_type(2))) float v2f;

__device__ __forceinline__ ushort f2bf(float f) {
    unsigned u = __float_as_uint(f);
    unsigned r = (u + 0x7fffu + ((u >> 16) & 1u)) >> 16;
    return (ushort)r;
}
__device__ __forceinline__ float bf2f(ushort u) {
    return __uint_as_float((unsigned)u << 16);
}
__device__ __forceinline__ v2f unpack2(unsigned u) {
    v2f r;
    r.x = __uint_as_float(u << 16);
    r.y = __uint_as_float(u & 0xffff0000u);
    return r;
}
// DPP-fused add: x + dpp(x); pure VALU, no LDS pipe
template <int CTRL>
__device__ __forceinline__ float dppadd(float x) {
    int y = __builtin_amdgcn_update_dpp(0, __float_as_int(x), CTRL, 0xF, 0xF, true);
    return x + __int_as_float(y);
}
__device__ __forceinline__ float rowsum16(float x) {
    x = dppadd<0xB1>(x);    // quad_perm [1,0,3,2]
    x = dppadd<0x4E>(x);    // quad_perm [2,3,0,1]
    x = dppadd<0x124>(x);   // row_ror:4
    x = dppadd<0x128>(x);   // row_ror:8
    return x;
}
__device__ __forceinline__ float rowsum32(float x) {
    x = rowsum16(x);
    float t = __int_as_float(__builtin_amdgcn_ds_swizzle(__float_as_int(x), 0x401F));
    return x + t;
}

// ---------- fused preprocess: x->bf16, 4 weight transposes, dst histogram ----------
#define PB_HIST 1250
#define PB_CONV 5000
#define PB_T1   512
#define PB_T2   128
#define PB_TOTAL (PB_HIST + PB_CONV + 2 * PB_T1 + 2 * PB_T2)  // 7530
__global__ __launch_bounds__(256) void preprocess(
    const float* __restrict__ x, ushort* __restrict__ xbf,
    const float* __restrict__ Wl1, const float* __restrict__ Wr1,
    const float* __restrict__ Wl2, const float* __restrict__ Wr2,
    ushort* __restrict__ wt1, ushort* __restrict__ wt2,
    const int* __restrict__ dst, int* __restrict__ cnt) {
    int b = blockIdx.x, t = threadIdx.x;
    if (b < PB_HIST) {
        int i = b * 256 + t;
        if (i < N_EDGES) atomicAdd(&cnt[dst[i]], 1);
    } else if (b < PB_HIST + PB_CONV) {
        int i = (b - PB_HIST) * 256 + t;   // float4 index
        if (i < N_NODES * F_IN / 4) {
            float4 v = ((const float4*)x)[i];
            ushort4 o;
            o.x = f2bf(v.x); o.y = f2bf(v.y); o.z = f2bf(v.z); o.w = f2bf(v.w);
            ((ushort4*)xbf)[i] = o;
        }
    } else if (b < PB_HIST + PB_CONV + 2 * PB_T1) {
        int lb = b - PB_HIST - PB_CONV;
        const float* W = (lb < PB_T1) ? Wl1 : Wr1;
        ushort* Wt = wt1 + ((lb < PB_T1) ? 0 : D1 * F_IN);
        int i = (lb % PB_T1) * 256 + t;    // i = n*256 + k, Kd=256
        if (i < D1 * F_IN) {
            int n = i >> 8, k = i & 255;
            Wt[i] = f2bf(W[(size_t)k * D1 + n]);
        }
    } else {
        int lb = b - PB_HIST - PB_CONV - 2 * PB_T1;
        const float* W = (lb < PB_T2) ? Wl2 : Wr2;
        ushort* Wt = wt2 + ((lb < PB_T2) ? 0 : NCLS * D1);
        int i = (lb % PB_T2) * 256 + t;    // Kd=512
        if (i < NCLS * D1) {
            int n = i >> 9, k = i & 511;
            Wt[i] = f2bf(W[(size_t)k * NCLS + n]);
        }
    }
}

// ---------- CSR scan + scatter ----------
__global__ __launch_bounds__(256) void scan_local(const int* __restrict__ cnt,
                                                  int* __restrict__ pscan,
                                                  int* __restrict__ bsum, int n) {
    int tid = threadIdx.x;
    int i = blockIdx.x * 256 + tid;
    int lane = tid & 63, wave = tid >> 6;
    int v = (i < n) ? cnt[i] : 0;
    int x = v;
    #pragma unroll
    for (int d = 1; d < 64; d <<= 1) {
        int y = __shfl_up(x, d);
        if (lane >= d) x += y;
    }
    __shared__ int wsum[4];
    if (lane == 63) wsum[wave] = x;
    __syncthreads();
    int woff = 0;
    for (int w2 = 0; w2 < wave; w2++) woff += wsum[w2];
    int incl = x + woff;
    if (i < n) pscan[i] = incl;
    if (tid == 255) bsum[blockIdx.x] = incl;
}

// finalize with inline reduction of bsum[0..blockIdx-1] (replaces scan_block)
__global__ __launch_bounds__(256) void scan_finalize(const int* __restrict__ cnt,
                                                     const int* __restrict__ pscan,
                                                     const int* __restrict__ bsum,
                                                     int* __restrict__ row_ptr,
                                                     int* __restrict__ cursor, int n) {
    int t = threadIdx.x;
    int lane = t & 63, wave = t >> 6;
    int v = (t < SCAN_BLOCKS && t < blockIdx.x) ? bsum[t] : 0;
    #pragma unroll
    for (int mask = 1; mask < 64; mask <<= 1) v += __shfl_xor(v, mask);
    __shared__ int ws[4];
    __shared__ int soff;
    if (lane == 0) ws[wave] = v;
    __syncthreads();
    if (t == 0) soff = ws[0] + ws[1] + ws[2] + ws[3];
    __syncthreads();
    int i = blockIdx.x * 256 + t;
    if (i < n) {
        int incl = pscan[i] + soff;
        row_ptr[i + 1] = incl;
        cursor[i] = incl - cnt[i];
    }
    if (i == 0) row_ptr[0] = 0;
}

__global__ void scatter_kernel(const int* __restrict__ src, const int* __restrict__ dst,
                               int* __restrict__ cursor, int* __restrict__ csr_src, int E) {
    int i = blockIdx.x * 256 + threadIdx.x;
    if (i < E) {
        int d = dst[i];
        int pos = atomicAdd(&cursor[d], 1);
        csr_src[pos] = src[i];
    }
}

// ---------- bf16 MFMA GEMM 128x128 tile: C[M,N] = A[M,K] @ Bt[N,K]^T ----------
// 256 threads = 4 waves; wave w computes 64x64 quadrant (row half w>>1, col half w&1).
// N must be a multiple of 128.
#define APAD 40
__global__ __launch_bounds__(256) void gemm_mfma_128x128(
    const ushort* __restrict__ A, const ushort* __restrict__ Bt,
    ushort* __restrict__ C, int M, int N, int K) {
    __shared__ ushort As[128 * APAD];
    __shared__ ushort Bs[128 * APAD];
    int tid = threadIdx.x;
    int rowBase = blockIdx.y * 128, colBase = blockIdx.x * 128;
    int wave = tid >> 6, lane = tid & 63;
    int quad = lane >> 4, m16 = lane & 15;
    int rh = wave >> 1, chf = wave & 1;
    floatx4 acc[4][4];
    #pragma unroll
    for (int i = 0; i < 4; i++)
        #pragma unroll
        for (int j = 0; j < 4; j++) acc[i][j] = (floatx4){0.f, 0.f, 0.f, 0.f};

    for (int k0 = 0; k0 < K; k0 += 32) {
        #pragma unroll
        for (int i = 0; i < 2; i++) {
            int idx = i * 256 + tid;
            int r = idx >> 2, kq = (idx & 3) * 8;
            int grow = rowBase + r;
            uint4 v = make_uint4(0, 0, 0, 0);
            if (grow < M) v = *(const uint4*)(A + (size_t)grow * K + k0 + kq);
            *(uint4*)&As[r * APAD + kq] = v;
            uint4 w = *(const uint4*)(Bt + (size_t)(colBase + r) * K + k0 + kq);
            *(uint4*)&Bs[r * APAD + kq] = w;
        }
        __syncthreads();
        short8 af[4], bf[4];
        #pragma unroll
        for (int i = 0; i < 4; i++)
            af[i] = *(short8*)&As[(rh * 64 + i * 16 + m16) * APAD + quad * 8];
        #pragma unroll
        for (int j = 0; j < 4; j++)
            bf[j] = *(short8*)&Bs[(chf * 64 + j * 16 + m16) * APAD + quad * 8];
        #pragma unroll
        for (int i = 0; i < 4; i++)
            #pragma unroll
            for (int j = 0; j < 4; j++)
                acc[i][j] = __builtin_amdgcn_mfma_f32_16x16x32_bf16(af[i], bf[j], acc[i][j], 0, 0, 0);
        __syncthreads();
    }
    // C/D layout: col=lane&15, row=quad*4+reg
    #pragma unroll
    for (int i = 0; i < 4; i++)
        #pragma unroll
        for (int j = 0; j < 4; j++)
            #pragma unroll
            for (int r = 0; r < 4; r++) {
                int row = rowBase + rh * 64 + i * 16 + quad * 4 + r;
                if (row < M) C[(size_t)row * N + colBase + chf * 64 + j * 16 + m16] = f2bf(acc[i][j][r]);
            }
}

// ---------- bf16 MFMA GEMM 128x64 tile (for narrow N) ----------
__global__ __launch_bounds__(256) void gemm_mfma_bt_bf16(
    const ushort* __restrict__ A, const ushort* __restrict__ Bt,
    ushort* __restrict__ C, int M, int N, int K) {
    __shared__ ushort As[128 * APAD];
    __shared__ ushort Bs[64 * APAD];
    int tid = threadIdx.x;
    int rowBase = blockIdx.y * 128, colBase = blockIdx.x * 64;
    int wave = tid >> 6, lane = tid & 63;
    int quad = lane >> 4, m16 = lane & 15;
    floatx4 acc[2][4];
    #pragma unroll
    for (int i = 0; i < 2; i++)
        #pragma unroll
        for (int j = 0; j < 4; j++) acc[i][j] = (floatx4){0.f, 0.f, 0.f, 0.f};

    for (int k0 = 0; k0 < K; k0 += 32) {
        #pragma unroll
        for (int i = 0; i < 2; i++) {
            int idx = i * 256 + tid;
            int r = idx >> 2, kq = (idx & 3) * 8;
            int grow = rowBase + r;
            uint4 v = make_uint4(0, 0, 0, 0);
            if (grow < M) v = *(const uint4*)(A + (size_t)grow * K + k0 + kq);
            *(uint4*)&As[r * APAD + kq] = v;
        }
        {
            int r = tid >> 2, kq = (tid & 3) * 8;
            uint4 v = *(const uint4*)(Bt + (size_t)(colBase + r) * K + k0 + kq);
            *(uint4*)&Bs[r * APAD + kq] = v;
        }
        __syncthreads();
        short8 a0 = *(short8*)&As[(wave * 32 + m16) * APAD + quad * 8];
        short8 a1 = *(short8*)&As[(wave * 32 + 16 + m16) * APAD + quad * 8];
        #pragma unroll
        for (int ct = 0; ct < 4; ct++) {
            short8 b = *(short8*)&Bs[(ct * 16 + m16) * APAD + quad * 8];
            acc[0][ct] = __builtin_amdgcn_mfma_f32_16x16x32_bf16(a0, b, acc[0][ct], 0, 0, 0);
            acc[1][ct] = __builtin_amdgcn_mfma_f32_16x16x32_bf16(a1, b, acc[1][ct], 0, 0, 0);
        }
        __syncthreads();
    }
    #pragma unroll
    for (int rt = 0; rt < 2; rt++)
        #pragma unroll
        for (int ct = 0; ct < 4; ct++)
            #pragma unroll
            for (int r = 0; r < 4; r++) {
                int row = rowBase + wave * 32 + rt * 16 + quad * 4 + r;
                if (row < M) C[(size_t)row * N + colBase + ct * 16 + m16] = f2bf(acc[rt][ct][r]);
            }
}

// ---------- layer-1 fused attention: 8-deep prefetch, DPP reductions ----------
// 128 thr/block, thread t owns channels 4t..4t+3 (16-lane head groups).
__global__ __launch_bounds__(128) void attn_l1_fused(
    const ushort* __restrict__ xlr, const float* __restrict__ att,
    const float* __restrict__ b1,
    const int* __restrict__ row_ptr, const int* __restrict__ csr_src,
    ushort* __restrict__ h1out) {
    int d = blockIdx.x, t = threadIdx.x;
    int start = row_ptr[d], deg = row_ptr[d + 1] - start;

    uint2 xru = *(const uint2*)(xlr + (size_t)d * 1024 + 512 + 4 * t);
    v2f xr01 = unpack2(xru.x), xr23 = unpack2(xru.y);
    float4 atv = *(const float4*)(att + 4 * t);
    v2f at6_01 = {0.6f * atv.x, 0.6f * atv.y}, at6_23 = {0.6f * atv.z, 0.6f * atv.w};
    v2f at4_01 = {0.4f * atv.x, 0.4f * atv.y}, at4_23 = {0.4f * atv.z, 0.4f * atv.w};

    float den = 0.f;
    v2f acc01 = {0.f, 0.f}, acc23 = {0.f, 0.f};

    if (deg > 0) {
        uint2 bufA[4], bufB[4];
        #pragma unroll
        for (int j = 0; j < 4; j++) {
            int s = csr_src[start + min(j, deg - 1)];
            bufA[j] = *(const uint2*)(xlr + (size_t)s * 1024 + 4 * t);
        }
        #pragma unroll
        for (int j = 0; j < 4; j++) {
            int s = csr_src[start + min(4 + j, deg - 1)];
            bufB[j] = *(const uint2*)(xlr + (size_t)s * 1024 + 4 * t);
        }
        for (int p0 = 0; p0 < deg; p0 += 8) {
            // ---- batch A: edges p0..p0+3 ----
            {
                uint2 u0 = bufA[0], u1 = bufA[1], u2 = bufA[2], u3 = bufA[3];
                #pragma unroll
                for (int j = 0; j < 4; j++) {
                    int p = p0 + 8 + j;
                    if (p < deg) {
                        int s = csr_src[start + p];
                        bufA[j] = *(const uint2*)(xlr + (size_t)s * 1024 + 4 * t);
                    }
                }
                v2f c01_0 = unpack2(u0.x), c23_0 = unpack2(u0.y);
                v2f c01_1 = unpack2(u1.x), c23_1 = unpack2(u1.y);
                v2f c01_2 = unpack2(u2.x), c23_2 = unpack2(u2.y);
                v2f c01_3 = unpack2(u3.x), c23_3 = unpack2(u3.y);
                v2f va, vb, sp;
                va = c01_0 + xr01; vb = c23_0 + xr23;
                sp = at6_01 * va + at4_01 * __builtin_elementwise_abs(va)
                   + at6_23 * vb + at4_23 * __builtin_elementwise_abs(vb);
                float s0 = sp.x + sp.y;
                va = c01_1 + xr01; vb = c23_1 + xr23;
                sp = at6_01 * va + at4_01 * __builtin_elementwise_abs(va)
                   + at6_23 * vb + at4_23 * __builtin_elementwise_abs(vb);
                float s1 = sp.x + sp.y;
                va = c01_2 + xr01; vb = c23_2 + xr23;
                sp = at6_01 * va + at4_01 * __builtin_elementwise_abs(va)
                   + at6_23 * vb + at4_23 * __builtin_elementwise_abs(vb);
                float s2 = sp.x + sp.y;
                va = c01_3 + xr01; vb = c23_3 + xr23;
                sp = at6_01 * va + at4_01 * __builtin_elementwise_abs(va)
                   + at6_23 * vb + at4_23 * __builtin_elementwise_abs(vb);
                float s3 = sp.x + sp.y;
                s0 = rowsum16(s0); s1 = rowsum16(s1);
                s2 = rowsum16(s2); s3 = rowsum16(s3);
                float e0 = (p0 + 0 < deg) ? __expf(s0) : 0.f;
                float e1 = (p0 + 1 < deg) ? __expf(s1) : 0.f;
                float e2 = (p0 + 2 < deg) ? __expf(s2) : 0.f;
                float e3 = (p0 + 3 < deg) ? __expf(s3) : 0.f;
                den += (e0 + e1) + (e2 + e3);
                v2f e0v = {e0, e0}, e1v = {e1, e1}, e2v = {e2, e2}, e3v = {e3, e3};
                acc01 = acc01 + e0v * c01_0 + e1v * c01_1 + e2v * c01_2 + e3v * c01_3;
                acc23 = acc23 + e0v * c23_0 + e1v * c23_1 + e2v * c23_2 + e3v * c23_3;
            }
            // ---- batch B: edges p0+4..p0+7 ----
            if (p0 + 4 < deg) {
                uint2 u0 = bufB[0], u1 = bufB[1], u2 = bufB[2], u3 = bufB[3];
                #pragma unroll
                for (int j = 0; j < 4; j++) {
                    int p = p0 + 12 + j;
                    if (p < deg) {
                        int s = csr_src[start + p];
                        bufB[j] = *(const uint2*)(xlr + (size_t)s * 1024 + 4 * t);
                    }
                }
                v2f c01_0 = unpack2(u0.x), c23_0 = unpack2(u0.y);
                v2f c01_1 = unpack2(u1.x), c23_1 = unpack2(u1.y);
                v2f c01_2 = unpack2(u2.x), c23_2 = unpack2(u2.y);
                v2f c01_3 = unpack2(u3.x), c23_3 = unpack2(u3.y);
                v2f va, vb, sp;
                va = c01_0 + xr01; vb = c23_0 + xr23;
                sp = at6_01 * va + at4_01 * __builtin_elementwise_abs(va)
                   + at6_23 * vb + at4_23 * __builtin_elementwise_abs(vb);
                float s0 = sp.x + sp.y;
                va = c01_1 + xr01; vb = c23_1 + xr23;
                sp = at6_01 * va + at4_01 * __builtin_elementwise_abs(va)
                   + at6_23 * vb + at4_23 * __builtin_elementwise_abs(vb);
                float s1 = sp.x + sp.y;
                va = c01_2 + xr01; vb = c23_2 + xr23;
                sp = at6_01 * va + at4_01 * __builtin_elementwise_abs(va)
                   + at6_23 * vb + at4_23 * __builtin_elementwise_abs(vb);
                float s2 = sp.x + sp.y;
                va = c01_3 + xr01; vb = c23_3 + xr23;
                sp = at6_01 * va + at4_01 * __builtin_elementwise_abs(va)
                   + at6_23 * vb + at4_23 * __builtin_elementwise_abs(vb);
                float s3 = sp.x + sp.y;
                s0 = rowsum16(s0); s1 = rowsum16(s1);
                s2 = rowsum16(s2); s3 = rowsum16(s3);
                float e0 = (p0 + 4 < deg) ? __expf(s0) : 0.f;
                float e1 = (p0 + 5 < deg) ? __expf(s1) : 0.f;
                float e2 = (p0 + 6 < deg) ? __expf(s2) : 0.f;
                float e3 = (p0 + 7 < deg) ? __expf(s3) : 0.f;
                den += (e0 + e1) + (e2 + e3);
                v2f e0v = {e0, e0}, e1v = {e1, e1}, e2v = {e2, e2}, e3v = {e3, e3};
                acc01 = acc01 + e0v * c01_0 + e1v * c01_1 + e2v * c01_2 + e3v * c01_3;
                acc23 = acc23 + e0v * c23_0 + e1v * c23_1 + e2v * c23_2 + e3v * c23_3;
            }
        }
    }
    float inv = 1.f / (den + 1e-16f);
    float4 bv = *(const float4*)(b1 + 4 * t);
    float o0 = acc01.x * inv + bv.x;
    float o1 = acc01.y * inv + bv.y;
    float o2 = acc23.x * inv + bv.z;
    float o3 = acc23.y * inv + bv.w;
    o0 = o0 > 0.f ? o0 : (__expf(o0) - 1.f);   // ELU
    o1 = o1 > 0.f ? o1 : (__expf(o1) - 1.f);
    o2 = o2 > 0.f ? o2 : (__expf(o2) - 1.f);
    o3 = o3 > 0.f ? o3 : (__expf(o3) - 1.f);
    ushort4 hv;
    hv.x = f2bf(o0); hv.y = f2bf(o1); hv.z = f2bf(o2); hv.w = f2bf(o3);
    *(ushort4*)(h1out + (size_t)d * D1 + 4 * t) = hv;
}

// ---------- layer-2 fused attention: half-wave per edge, 2 ch/lane ----------
__global__ __launch_bounds__(256) void attn_l2_fused(
    const ushort* __restrict__ ylr, const float* __restrict__ att2,
    const float* __restrict__ b2,
    const int* __restrict__ row_ptr, const int* __restrict__ csr_src,
    float* __restrict__ out) {
    int wave = threadIdx.x >> 6, lane = threadIdx.x & 63;
    int d = blockIdx.x * 4 + wave;
    if (d >= N_NODES) return;
    int half = lane >> 5, l31 = lane & 31;
    int start = row_ptr[d], deg = row_ptr[d + 1] - start;

    unsigned yru = *(const unsigned*)(ylr + (size_t)d * 128 + 64 + 2 * l31);
    v2f yr2 = unpack2(yru);
    float2 a2 = *(const float2*)(att2 + 2 * l31);
    v2f at6 = {0.6f * a2.x, 0.6f * a2.y};
    v2f at4 = {0.4f * a2.x, 0.4f * a2.y};

    float den = 0.f;
    v2f acc = {0.f, 0.f};

    if (deg > 0) {
        int S = (deg + 1) >> 1;                 // steps of 2 edges
        unsigned yv[4];
        #pragma unroll
        for (int j = 0; j < 4; j++) {
            int p = min(2 * j + half, deg - 1);
            int s = csr_src[start + p];
            yv[j] = *(const unsigned*)(ylr + (size_t)s * 128 + 2 * l31);
        }
        for (int i = 0; i < S; i++) {
            unsigned cu = yv[i & 3];
            int pf = i + 4;
            if (pf < S) {
                int p = min(2 * pf + half, deg - 1);
                int s = csr_src[start + p];
                yv[i & 3] = *(const unsigned*)(ylr + (size_t)s * 128 + 2 * l31);
            }
            v2f c2 = unpack2(cu);
            v2f v = c2 + yr2;
            v2f sp = at6 * v + at4 * __builtin_elementwise_abs(v);
            float sc = sp.x + sp.y;
            sc = rowsum32(sc);
            float e = (2 * i + half < deg) ? __expf(sc) : 0.f;
            den += e;
            v2f ev = {e, e};
            acc = acc + ev * c2;
        }
        den += __shfl_xor(den, 32);
        acc.x += __shfl_xor(acc.x, 32);
        acc.y += __shfl_xor(acc.y, 32);
    }
    if (half == 0) {
        float inv = 1.f / (den + 1e-16f);
        float2 bv = *(const float2*)(b2 + 2 * l31);
        float2 o;
        o.x = acc.x * inv + bv.x;
        o.y = acc.y * inv + bv.y;
        *(float2*)(out + (size_t)d * NCLS + 2 * l31) = o;
    }
}

extern "C" void kernel_launch(void* const* d_in, const int* in_sizes, int n_in,
                              void* d_out, int out_size, void* d_ws, size_t ws_size,
                              hipStream_t stream) {
    const float* x    = (const float*)d_in[0];
    const int*   edge = (const int*)d_in[1];
    const float* Wl1  = (const float*)d_in[2];
    const float* Wr1  = (const float*)d_in[3];
    const float* att1 = (const float*)d_in[4];
    const float* b1   = (const float*)d_in[5];
    const float* Wl2  = (const float*)d_in[6];
    const float* Wr2  = (const float*)d_in[7];
    const float* att2 = (const float*)d_in[8];
    const float* b2   = (const float*)d_in[9];
    float* out = (float*)d_out;

    const int* srcv = edge;
    const int* dstv = edge + N_EDGES;

    ushort* xbf  = (ushort*)d_ws;                        // N*256
    ushort* wt1  = xbf + (size_t)N_NODES * F_IN;         // 1024*256 (Wl1^T || Wr1^T)
    ushort* wt2  = wt1 + 2 * D1 * F_IN;                  // 128*512  (Wl2^T || Wr2^T)
    ushort* xlr  = wt2 + 2 * NCLS * D1;                  // N*1024 bf16
    ushort* h1   = xlr + (size_t)N_NODES * 2 * D1;       // N*512 bf16
    ushort* ylr  = h1 + (size_t)N_NODES * D1;            // N*128 bf16
    int* cnt     = (int*)(ylr + (size_t)N_NODES * 2 * NCLS);
    int* pscan   = cnt + N_NODES;                        // N
    int* bsum    = pscan + N_NODES;                      // 128
    int* row_ptr = bsum + 128;                           // N+1
    int* cursor  = row_ptr + N_NODES + 1;                // N
    int* csr_src = cursor + N_NODES;                     // E

    hipMemsetAsync(cnt, 0, N_NODES * sizeof(int), stream);
    preprocess<<<PB_TOTAL, 256, 0, stream>>>(x, xbf, Wl1, Wr1, Wl2, Wr2, wt1, wt2, dstv, cnt);
    scan_local<<<SCAN_BLOCKS, 256, 0, stream>>>(cnt, pscan, bsum, N_NODES);
    scan_finalize<<<SCAN_BLOCKS, 256, 0, stream>>>(cnt, pscan, bsum, row_ptr, cursor, N_NODES);
    scatter_kernel<<<N_EDGES / 256, 256, 0, stream>>>(srcv, dstv, cursor, csr_src, N_EDGES);

    // layer 1 projection (fused l+r): xlr[N][1024] bf16, 128x128 tiles
    gemm_mfma_128x128<<<dim3(2 * D1 / 128, (N_NODES + 127) / 128), 256, 0, stream>>>(
        xbf, wt1, xlr, N_NODES, 2 * D1, F_IN);
    attn_l1_fused<<<N_NODES, 128, 0, stream>>>(xlr, att1, b1, row_ptr, csr_src, h1);
    // layer 2 projection (fused l+r): ylr[N][128] bf16, 128x64 tiles (more blocks)
    gemm_mfma_bt_bf16<<<dim3(2 * NCLS / 64, (N_NODES + 127) / 128), 256, 0, stream>>>(
        h1, wt2, ylr, N_NODES, 2 * NCLS, D1);
    attn_l2_fused<<<(N_NODES + 3) / 4, 256, 0, stream>>>(ylr, att2, b2, row_ptr, csr_src, out);
}